// Round 26
// baseline (725.017 us; speedup 1.0000x reference)
//
#include <hip/hip_runtime.h>

// SelfAttention: x[2,2048,5120] -> QKV proj -> RoPE -> causal GQA attention -> out proj
// All matmuls in bf16 MFMA (16x16x32), f32 accum. Tolerance is bf16-grade (0.148 absmax).
// FINAL: proven configuration (724 us, absmax 0.039, reproduced 9x: r14/17/19-25).
// Attn LDS layout is load-bearing: DO NOT modify P_lds/Ks/Vs geometry (occupancy
// experiments raced). cvt5 merge regressed (r18); separate wo convert is faster.

typedef unsigned short u16;
typedef __bf16 bf16x8 __attribute__((ext_vector_type(8)));
typedef __bf16 bf16x4 __attribute__((ext_vector_type(4)));
typedef float f32x4 __attribute__((ext_vector_type(4)));

__device__ __forceinline__ u16 f2bf(float f) {
  unsigned u = __builtin_bit_cast(unsigned, f);
  u += 0x7fff + ((u >> 16) & 1);   // RNE
  return (u16)(u >> 16);
}
__device__ __forceinline__ float bf2f(u16 h) {
  unsigned u = ((unsigned)h) << 16;
  return __builtin_bit_cast(float, u);
}

__device__ __forceinline__ float exp2_hw(float x) {
#if __has_builtin(__builtin_amdgcn_exp2f)
  return __builtin_amdgcn_exp2f(x);   // v_exp_f32: D = 2^S0
#else
  return __expf(x * 0.6931471805599453f);
#endif
}

__device__ __forceinline__ void gload_lds16(const u16* g, u16* lds) {
  __builtin_amdgcn_global_load_lds(
      (const __attribute__((address_space(1))) void*)g,
      (__attribute__((address_space(3))) void*)lds, 16, 0, 0);
}

__device__ __forceinline__ f32x4 mfma16(bf16x8 a, bf16x8 b, f32x4 c) {
  return __builtin_amdgcn_mfma_f32_16x16x32_bf16(a, b, c, 0, 0, 0);
}

#define VMW(N) asm volatile("s_waitcnt vmcnt(" #N ")" ::: "memory")
#define BAR()  __builtin_amdgcn_s_barrier()

// ---------------- f32 -> bf16 bulk convert (single, 4 segments) ----------------
__global__ __launch_bounds__(256) void cvt4_kernel(const float4* __restrict__ s0,
                                                   const float4* __restrict__ s1,
                                                   const float4* __restrict__ s2,
                                                   const float4* __restrict__ s3,
                                                   uint2* __restrict__ d0,
                                                   uint2* __restrict__ d1,
                                                   uint2* __restrict__ d2,
                                                   uint2* __restrict__ d3,
                                                   int n0, int n1, int n2, int n3) {
  int total = n0 + n1 + n2 + n3;
  for (int i = blockIdx.x * blockDim.x + threadIdx.x; i < total;
       i += gridDim.x * blockDim.x) {
    const float4* s; uint2* d; int j = i;
    if (j < n0) { s = s0; d = d0; }
    else if ((j -= n0) < n1) { s = s1; d = d1; }
    else if ((j -= n1) < n2) { s = s2; d = d2; }
    else { j -= n2; s = s3; d = d3; }
    float4 v = s[j];
    d[j] = make_uint2((unsigned)f2bf(v.x) | ((unsigned)f2bf(v.y) << 16),
                      (unsigned)f2bf(v.z) | ((unsigned)f2bf(v.w) << 16));
  }
}

// ---------------- f32 -> bf16 bulk convert (single segment, for wo) ------------
__global__ __launch_bounds__(256) void cvt_kernel(const float4* __restrict__ in,
                                                  uint2* __restrict__ out, int n4) {
  int i = blockIdx.x * blockDim.x + threadIdx.x;
  if (i >= n4) return;
  float4 v = in[i];
  unsigned lo = (unsigned)f2bf(v.x) | ((unsigned)f2bf(v.y) << 16);
  unsigned hi = (unsigned)f2bf(v.z) | ((unsigned)f2bf(v.w) << 16);
  out[i] = make_uint2(lo, hi);
}

// ---------------- RoPE in-place on bf16 [*, nheads, 64 pairs] ----------------
__global__ __launch_bounds__(256) void rope_kernel(u16* __restrict__ t,
                                                   const float* __restrict__ fcos,
                                                   const float* __restrict__ fsin,
                                                   int hsh, float scale, int total) {
  int idx = blockIdx.x * blockDim.x + threadIdx.x;
  if (idx >= total) return;
  int j = idx & 63;
  int s = (idx >> (6 + hsh)) & 2047;
  float c = fcos[s * 64 + j], sn = fsin[s * 64 + j];
  unsigned* p = (unsigned*)(t + (size_t)idx * 2);
  unsigned v = *p;
  float tr = bf2f((u16)(v & 0xffffu)), ti = bf2f((u16)(v >> 16));
  float orr = (tr * c - ti * sn) * scale;
  float oi  = (tr * sn + ti * c) * scale;
  *p = (unsigned)f2bf(orr) | ((unsigned)f2bf(oi) << 16);
}

// ---------------- bf16 NT GEMM 128x128 ----------------
// MODE 0: bf16 C[M][N]; MODE 2: transposed V store; MODE 3: merged K|V projection
// (B = [wk;wv] contiguous, N=2048; gn<1024 -> K stride 1024, else VT at +4Mi elems).
template <int MODE>
__global__ __launch_bounds__(256) void gemm_bt(const u16* __restrict__ A,
                                               const u16* __restrict__ B,
                                               void* __restrict__ Cout,
                                               int M, int N, int K) {
  __shared__ u16 As[8192];  // [128][64] bf16, chunk c (16B) of row r stored at c^(r&7)
  __shared__ u16 Bs[8192];
  const int tid = threadIdx.x;
  const int lane = tid & 63, wave = tid >> 6;
  const int wm = wave >> 1, wn = wave & 1;
  int gx = gridDim.x, gy = gridDim.y, nwg = gx * gy;
  int orig = blockIdx.y * gx + blockIdx.x;
  int mb, nb;
  if ((gx & 1) == 0 && (gy & 3) == 0 && (nwg & 7) == 0) {
    // XCDs arranged 4 (m) x 2 (n); per-XCD tile (gy/4) x (gx/2) blocks
    int x = orig & 7, idx = orig >> 3;
    int hy = gy >> 2, qx = gx >> 1;
    mb = (x >> 1) * hy + (idx % hy);
    nb = (x & 1) * qx + (idx / hy);
  } else {
    mb = orig / gx; nb = orig % gx;
  }
  const int m0 = mb * 128, n0 = nb * 128;
  const int lc = lane & 15, lg = lane >> 4;

  f32x4 acc[4][4] = {};
  const int sr = tid >> 3, sc = tid & 7;

  for (int kt = 0; kt < K; kt += 64) {
    __syncthreads();
#pragma unroll
    for (int q = 0; q < 4; ++q) {
      int r = q * 32 + sr;
      int cc = sc ^ (r & 7);
      gload_lds16(A + (size_t)(m0 + r) * K + kt + cc * 8, &As[q * 2048 + tid * 8]);
      gload_lds16(B + (size_t)(n0 + r) * K + kt + cc * 8, &Bs[q * 2048 + tid * 8]);
    }
    __syncthreads();
#pragma unroll
    for (int ks = 0; ks < 2; ++ks) {
      bf16x8 af[4], bfr[4];
#pragma unroll
      for (int m = 0; m < 4; ++m) {
        int r = wm * 64 + m * 16 + lc;
        int gc = ks * 4 + lg;
        af[m] = *(const bf16x8*)&As[r * 64 + ((gc ^ (r & 7)) * 8)];
      }
#pragma unroll
      for (int n = 0; n < 4; ++n) {
        int r = wn * 64 + n * 16 + lc;
        int gc = ks * 4 + lg;
        bfr[n] = *(const bf16x8*)&Bs[r * 64 + ((gc ^ (r & 7)) * 8)];
      }
#pragma unroll
      for (int m = 0; m < 4; ++m)
#pragma unroll
        for (int n = 0; n < 4; ++n)
          acc[m][n] = mfma16(af[m], bfr[n], acc[m][n]);
    }
  }

  // epilogue: C/D layout col=lane&15, row=(lane>>4)*4+i  [m89-verified]
#pragma unroll
  for (int m = 0; m < 4; ++m) {
#pragma unroll
    for (int n = 0; n < 4; ++n) {
#pragma unroll
      for (int i = 0; i < 4; ++i) {
        int gm = m0 + wm * 64 + m * 16 + lg * 4 + i;
        int gn = n0 + wn * 64 + n * 16 + lc;
        float v = acc[m][n][i];
        if (MODE == 0) {
          ((u16*)Cout)[(size_t)gm * N + gn] = f2bf(v);
        } else if (MODE == 2) {
          size_t addr = ((size_t)((gm >> 11) * 8 + (gn >> 7)) * 128 + (gn & 127)) * 2048 +
                        (gm & 2047);
          ((u16*)Cout)[addr] = f2bf(v);
        } else {  // MODE 3: merged K|V
          if (gn < 1024) {
            ((u16*)Cout)[(size_t)gm * 1024 + gn] = f2bf(v);
          } else {
            int gnv = gn - 1024;
            size_t addr = 4194304ull +
                          ((size_t)((gm >> 11) * 8 + (gnv >> 7)) * 128 + (gnv & 127)) * 2048 +
                          (gm & 2047);
            ((u16*)Cout)[addr] = f2bf(v);
          }
        }
      }
    }
  }
}

// ---------------- bf16 NT GEMM 256x256, 4-phase READ-AHEAD pipeline ----------
// (round-14 version — 219 us / ~785 TF, MfmaUtil 33.5%)
template <int OUT_F32>
__global__ __launch_bounds__(512, 2) void gemm256(const u16* __restrict__ A,
                                                  const u16* __restrict__ B,
                                                  void* __restrict__ Cout,
                                                  int M, int N, int K) {
  __shared__ u16 lds[2][2][2][8192];  // [buf][A=0/B=1][half][128*64]
  __shared__ u16 dummy[4096];
  const int tid = threadIdx.x, lane = tid & 63, wave = tid >> 6;
  const int wm = wave >> 2;            // A half (M)
  const int wn = wave & 3;             // N quarter
  const int lc = lane & 15, lg = lane >> 4;
  const int bh = wn >> 1;              // B half this wave reads
  const int bs64 = (wn & 1) * 64;      // row slice within B half
  const int str = tid >> 3, ssc = tid & 7;

  int gx = gridDim.x, gy = gridDim.y;
  int orig = blockIdx.y * gx + blockIdx.x;
  int mb, nb;
  if ((gx & 3) == 0 && (gy & 1) == 0) {
    // XCDs arranged 2 (m) x 4 (n); per-XCD tile (gy/2) x (gx/4) blocks
    int x = orig & 7, idx = orig >> 3;
    int hy = gy >> 1, qx = gx >> 2;
    mb = (x >> 2) * hy + (idx % hy);
    nb = (x & 3) * qx + (idx / hy);
  } else {
    mb = orig / gx; nb = orig % gx;
  }
  const int m0 = mb * 256, n0 = nb * 256;

  auto stageA = [&](int buf, int kcol, int r0, bool real) {
    int r = r0 + str, cc = ssc ^ (r & 7);
    const u16* s = A + (size_t)(m0 + r) * K + kcol + cc * 8;
    u16* d0 = real ? &lds[buf][0][0][r0 * 64] : dummy;
    u16* d1 = real ? &lds[buf][0][1][r0 * 64] : dummy;
    gload_lds16(s, d0 + tid * 8);
    gload_lds16(s + (size_t)128 * K, d1 + tid * 8);
  };
  auto stageB = [&](int buf, int kcol, int half, bool real) {
    int r = str, cc = ssc ^ (r & 7);
    int r2 = 64 + str, cc2 = ssc ^ (r2 & 7);
    const u16* s = B + (size_t)(n0 + half * 128) * K + kcol;
    u16* d0 = real ? &lds[buf][1][half][0] : dummy;
    u16* d1 = real ? &lds[buf][1][half][4096] : dummy;
    gload_lds16(s + (size_t)r * K + cc * 8, d0 + tid * 8);
    gload_lds16(s + (size_t)r2 * K + cc2 * 8, d1 + tid * 8);
  };

  f32x4 acc[8][4] = {};
  bf16x8 afk[4][2], bfk[4][2];

  const int nk = K >> 6;
  stageB(0, 0, 0, true);
  stageA(0, 0, 0, true);
  stageB(0, 0, 1, true);
  stageA(0, 0, 64, true);
  stageB(1, 64, 0, true);
  stageA(1, 64, 0, true);
  VMW(6);
  BAR();
  {  // preload af_lo(0), bfv01(0)
    const u16* Ab = &lds[0][0][wm][0];
    const u16* Bb = &lds[0][1][bh][0];
#pragma unroll
    for (int m = 0; m < 4; ++m)
#pragma unroll
      for (int kg = 0; kg < 2; ++kg) {
        int r = m * 16 + lc;
        afk[m][kg] = *(const bf16x8*)&Ab[r * 64 + (((kg * 4 + lg) ^ (r & 7)) * 8)];
      }
#pragma unroll
    for (int n = 0; n < 2; ++n)
#pragma unroll
      for (int kg = 0; kg < 2; ++kg) {
        int r = bs64 + n * 16 + lc;
        bfk[n][kg] = *(const bf16x8*)&Bb[r * 64 + (((kg * 4 + lg) ^ (r & 7)) * 8)];
      }
  }

  for (int t = 0; t < nk; ++t) {
    const int c = t & 1;
    const int t1 = t + 1, t2 = t + 2;
    const int kc1 = (t1 < nk ? t1 : nk - 1) << 6;
    const int kc2 = (t2 < nk ? t2 : nk - 1) << 6;
    const bool h1 = t1 < nk, h2 = t2 < nk;
    const u16* Ab = &lds[c][0][wm][0];
    const u16* Bb = &lds[c][1][bh][0];
    const u16* Abn = &lds[c ^ 1][0][wm][0];
    const u16* Bbn = &lds[c ^ 1][1][bh][0];

    // ---- p1: MFMA m0-3 x n0-1 ; read bfv23(t) ----
    stageB(t1 & 1, kc1, 1, h1);      // B1(t+1)
    BAR();
    __builtin_amdgcn_s_setprio(1);
#pragma unroll
    for (int m = 0; m < 4; ++m)
#pragma unroll
      for (int n = 0; n < 2; ++n)
#pragma unroll
        for (int kg = 0; kg < 2; ++kg)
          acc[m][n] = mfma16(afk[m][kg], bfk[n][kg], acc[m][n]);
    __builtin_amdgcn_s_setprio(0);
#pragma unroll
    for (int n = 2; n < 4; ++n)
#pragma unroll
      for (int kg = 0; kg < 2; ++kg) {
        int r = bs64 + n * 16 + lc;
        bfk[n][kg] = *(const bf16x8*)&Bb[r * 64 + (((kg * 4 + lg) ^ (r & 7)) * 8)];
      }
    BAR();

    // ---- p2: MFMA m0-3 x n2-3 ; read af_hi(t) ----
    VMW(6);                          // drains Ah(t) (4-phase slack)
    stageA(t1 & 1, kc1, 64, h1);     // Ah(t+1)
    BAR();
    __builtin_amdgcn_s_setprio(1);
#pragma unroll
    for (int m = 0; m < 4; ++m)
#pragma unroll
      for (int n = 2; n < 4; ++n)
#pragma unroll
        for (int kg = 0; kg < 2; ++kg)
          acc[m][n] = mfma16(afk[m][kg], bfk[n][kg], acc[m][n]);
    __builtin_amdgcn_s_setprio(0);
#pragma unroll
    for (int m = 0; m < 4; ++m)
#pragma unroll
      for (int kg = 0; kg < 2; ++kg) {
        int r = 64 + m * 16 + lc;
        afk[m][kg] = *(const bf16x8*)&Ab[r * 64 + (((kg * 4 + lg) ^ (r & 7)) * 8)];
      }
    BAR();

    // ---- p3: MFMA m4-7 x n0-1 ; read bfv01(t+1) from next buf ----
    VMW(2);                          // drains B0(t+1), Al(t+1), B1(t+1)
    stageB(t2 & 1, kc2, 0, h2);      // B0(t+2)
    BAR();
    __builtin_amdgcn_s_setprio(1);
#pragma unroll
    for (int m = 0; m < 4; ++m)
#pragma unroll
      for (int n = 0; n < 2; ++n)
#pragma unroll
        for (int kg = 0; kg < 2; ++kg)
          acc[4 + m][n] = mfma16(afk[m][kg], bfk[n][kg], acc[4 + m][n]);
    __builtin_amdgcn_s_setprio(0);
#pragma unroll
    for (int n = 0; n < 2; ++n)
#pragma unroll
      for (int kg = 0; kg < 2; ++kg) {
        int r = bs64 + n * 16 + lc;
        bfk[n][kg] = *(const bf16x8*)&Bbn[r * 64 + (((kg * 4 + lg) ^ (r & 7)) * 8)];
      }
    BAR();

    // ---- p4: MFMA m4-7 x n2-3 ; read af_lo(t+1) from next buf ----
    stageA(t2 & 1, kc2, 0, h2);      // Al(t+2)
    BAR();
    __builtin_amdgcn_s_setprio(1);
#pragma unroll
    for (int m = 0; m < 4; ++m)
#pragma unroll
      for (int n = 2; n < 4; ++n)
#pragma unroll
        for (int kg = 0; kg < 2; ++kg)
          acc[4 + m][n] = mfma16(afk[m][kg], bfk[n][kg], acc[4 + m][n]);
    __builtin_amdgcn_s_setprio(0);
#pragma unroll
    for (int m = 0; m < 4; ++m)
#pragma unroll
      for (int kg = 0; kg < 2; ++kg) {
        int r = m * 16 + lc;
        afk[m][kg] = *(const bf16x8*)&Abn[r * 64 + (((kg * 4 + lg) ^ (r & 7)) * 8)];
      }
    BAR();
  }

  // epilogue: C/D layout col=lane&15, row=(lane>>4)*4+i
#pragma unroll
  for (int m = 0; m < 8; ++m) {
#pragma unroll
    for (int n = 0; n < 4; ++n) {
#pragma unroll
      for (int i = 0; i < 4; ++i) {
        int gm = m0 + wm * 128 + m * 16 + lg * 4 + i;
        int gn = n0 + wn * 64 + n * 16 + lc;
        float v = acc[m][n][i];
        if (OUT_F32) ((float*)Cout)[(size_t)gm * N + gn] = v;
        else         ((u16*)Cout)[(size_t)gm * N + gn] = f2bf(v);
      }
    }
  }
}

// ---------------- causal GQA flash attention (v5: QBLK=128, fused Q-RoPE) -----
// Proven kernel (absmax 0.039, stable across timed replays, 9 reproductions).
// grid (S/128, HQ, B), 512 thr = 8 waves; P_lds stride 72 — DO NOT CHANGE.
__global__ __launch_bounds__(512) void attn_kernel(const u16* __restrict__ Q,
                                                   const u16* __restrict__ Kg,
                                                   const u16* __restrict__ VT,
                                                   const float* __restrict__ fcos,
                                                   const float* __restrict__ fsin,
                                                   u16* __restrict__ AO) {
  __shared__ u16 Ks[2][8192];        // [kv 64][d 128] per buf, chunk c at c^(r&15)
  __shared__ u16 Vs[2][8192];        // [d 128][kv 64] per buf, chunk c at c^(r&7)
  __shared__ u16 P_lds[8][16 * 72];  // per-wave P [q 16][kv 64], stride 72
  const int tid = threadIdx.x, lane = tid & 63, w = tid >> 6;
  const int qt = (int)gridDim.x - 1 - (int)blockIdx.x;  // heavy blocks first
  const int h = blockIdx.y, b = blockIdx.z;
  const int hkv = h >> 2;
  const int q0 = qt * 128;
  const int lc = lane & 15, lg = lane >> 4;

  // Q fragments + in-register RoPE (+ exp2 scale). Pair j = ks*16 + lg*4 + p.
  const float qs = 0.12751743558818574f;  // log2(e)/sqrt(128)
  const int srow = q0 + w * 16 + lc;      // this lane's q row (within batch)
  bf16x8 qf[4];
  {
    const size_t qrow = ((size_t)(b * 2048 + srow) * 32 + h) * 128;
#pragma unroll
    for (int ks = 0; ks < 4; ++ks) {
      bf16x8 raw = *(const bf16x8*)&Q[qrow + ks * 32 + lg * 8];
      float4 c4 = *(const float4*)&fcos[srow * 64 + ks * 16 + lg * 4];
      float4 s4 = *(const float4*)&fsin[srow * 64 + ks * 16 + lg * 4];
#pragma unroll
      for (int p = 0; p < 4; ++p) {
        float cc = (&c4.x)[p], ss = (&s4.x)[p];
        float tr = (float)raw[2 * p], ti = (float)raw[2 * p + 1];
        qf[ks][2 * p]     = (__bf16)((tr * cc - ti * ss) * qs);
        qf[ks][2 * p + 1] = (__bf16)((tr * ss + ti * cc) * qs);
      }
    }
  }

  f32x4 o[8] = {};
  f32x4 lsum = {0.f, 0.f, 0.f, 0.f};

  const int nsteps = 2 * qt + 2;
  const size_t kpanel = ((size_t)b * 2048 * 8 + hkv) * 128;
  const size_t vpanel = ((size_t)(b * 8 + hkv) * 128) * 2048;

  auto stage = [&](int buf, int step) {
    const int kv0 = step * 64;
#pragma unroll
    for (int p = 0; p < 2; ++p) {  // K tile: 64 rows x 256B, 512 thr
      int r = p * 32 + (tid >> 4);
      int cc = (tid & 15) ^ (r & 15);
      gload_lds16(Kg + kpanel + (size_t)(kv0 + r) * 1024 + cc * 8,
                  &Ks[buf][p * 4096 + tid * 8]);
    }
#pragma unroll
    for (int p = 0; p < 2; ++p) {  // VT tile: 128 rows x 128B
      int r = p * 64 + (tid >> 3);
      int cc = (tid & 7) ^ (r & 7);
      gload_lds16(VT + vpanel + (size_t)r * 2048 + kv0 + cc * 8,
                  &Vs[buf][p * 4096 + tid * 8]);
    }
  };

  stage(0, 0);

  for (int step = 0; step < nsteps; ++step) {
    const int kv0 = step * 64;
    __syncthreads();
    if (step + 1 < nsteps) stage((step + 1) & 1, step + 1);
    const u16* kb = Ks[step & 1];
    const u16* vb = Vs[step & 1];

    f32x4 s[4];
#pragma unroll
    for (int nf = 0; nf < 4; ++nf) s[nf] = f32x4{0.f, 0.f, 0.f, 0.f};
    __builtin_amdgcn_s_setprio(1);
#pragma unroll
    for (int ks = 0; ks < 4; ++ks) {
#pragma unroll
      for (int nf = 0; nf < 4; ++nf) {
        int r = nf * 16 + lc;
        int gc = ks * 4 + lg;
        bf16x8 kf = *(const bf16x8*)&kb[r * 128 + ((gc ^ (r & 15)) * 8)];
        s[nf] = mfma16(kf, qf[ks], s[nf]);  // swapped: S[kv][q=lc]
      }
    }
    __builtin_amdgcn_s_setprio(0);

    if (step >= 2 * qt) {  // diagonal region (last two steps)
      int q = srow;
#pragma unroll
      for (int nf = 0; nf < 4; ++nf) {
#pragma unroll
        for (int i = 0; i < 4; ++i) {
          int kv = kv0 + nf * 16 + lg * 4 + i;
          if (kv > q) s[nf][i] = -1e30f;
        }
      }
    }

#pragma unroll
    for (int nf = 0; nf < 4; ++nf) {
#pragma unroll
      for (int i = 0; i < 4; ++i) s[nf][i] = exp2_hw(s[nf][i]);
      lsum += s[nf];
      bf16x4 pw = {(__bf16)s[nf][0], (__bf16)s[nf][1], (__bf16)s[nf][2], (__bf16)s[nf][3]};
      *(bf16x4*)&P_lds[w][lc * 72 + nf * 16 + lg * 4] = pw;
    }
    asm volatile("s_waitcnt lgkmcnt(0)" ::: "memory");
    __builtin_amdgcn_sched_barrier(0);

    bf16x8 pa[2];
#pragma unroll
    for (int ksv = 0; ksv < 2; ++ksv)
      pa[ksv] = *(const bf16x8*)&P_lds[w][lc * 72 + ksv * 32 + lg * 8];

    __builtin_amdgcn_s_setprio(1);
#pragma unroll
    for (int nfd = 0; nfd < 8; ++nfd) {
#pragma unroll
      for (int ksv = 0; ksv < 2; ++ksv) {
        int r = nfd * 16 + lc;
        int gc = ksv * 4 + lg;
        bf16x8 vf = *(const bf16x8*)&vb[r * 64 + ((gc ^ (r & 7)) * 8)];
        o[nfd] = mfma16(pa[ksv], vf, o[nfd]);
      }
    }
    __builtin_amdgcn_s_setprio(0);
  }

  float t = lsum[0] + lsum[1] + lsum[2] + lsum[3];
  t += __shfl_xor(t, 16, 64);
  t += __shfl_xor(t, 32, 64);
  float linv[4];
#pragma unroll
  for (int i = 0; i < 4; ++i) linv[i] = 1.0f / __shfl(t, lg * 4 + i, 64);

#pragma unroll
  for (int nfd = 0; nfd < 8; ++nfd)
#pragma unroll
    for (int i = 0; i < 4; ++i) {
      int row = q0 + w * 16 + lg * 4 + i;
      AO[((size_t)(b * 2048 + row) * 32 + h) * 128 + nfd * 16 + lc] =
          f2bf(o[nfd][i] * linv[i]);
    }
}

extern "C" void kernel_launch(void* const* d_in, const int* in_sizes, int n_in,
                              void* d_out, int out_size, void* d_ws, size_t ws_size,
                              hipStream_t stream) {
  const float* x    = (const float*)d_in[0];
  const float* fcos = (const float*)d_in[1];
  const float* fsin = (const float*)d_in[2];
  const float* wq   = (const float*)d_in[3];
  const float* wk   = (const float*)d_in[4];
  const float* wv   = (const float*)d_in[5];
  const float* wo   = (const float*)d_in[6];
  float* out = (float*)d_out;

  char* ws = (char*)d_ws;
  u16* xb  = (u16*)(ws + 0);             // x bf16  -> later AO
  u16* wqb = (u16*)(ws + 41943040ull);   // wq bf16 -> later wo bf16
  u16* wkb = (u16*)(ws + 83886080ull);   // [wk; wv] CONTIGUOUS (wkv = [2048][5120])
  u16* wvb = (u16*)(ws + 94371840ull);
  u16* Qb  = (u16*)(ws + 104857600ull);
  u16* Kb  = (u16*)(ws + 138412032ull);  // [Kb; VTb] CONTIGUOUS (VT at +4Mi elems)
  u16* VTb = (u16*)(ws + 146800640ull);  // total 155,189,248 B
  u16* AOb = xb;
  u16* wob = wqb;

  // one launch converts x, wq, wk, wv (wo waits: its dst aliases wq's slot)
  cvt4_kernel<<<dim3(2048), dim3(256), 0, stream>>>(
      (const float4*)x, (const float4*)wq, (const float4*)wk, (const float4*)wv,
      (uint2*)xb, (uint2*)wqb, (uint2*)wkb, (uint2*)wvb,
      2 * 2048 * 5120 / 4, 4096 * 5120 / 4, 1024 * 5120 / 4, 1024 * 5120 / 4);

  dim3 blk(256);
  gemm256<0><<<dim3(16, 16), dim3(512), 0, stream>>>(xb, wqb, Qb, 4096, 4096, 5120);
  // merged K+V projection: gemm_bt with B=[wk;wv], N=2048; MODE 3 epilogue
  gemm_bt<3><<<dim3(16, 32), blk, 0, stream>>>(xb, wkb, Kb, 4096, 2048, 5120);

  cvt_kernel<<<dim3(5242880 / 256), blk, 0, stream>>>((const float4*)wo, (uint2*)wob,
                                                      5242880);  // wq dead; reuse slot

  // K-RoPE (proven kernel); Q-RoPE (+ scale) is fused into attn_kernel.
  rope_kernel<<<dim3(2097152 / 256), blk, 0, stream>>>(Kb, fcos, fsin, 3, 1.0f, 2097152);

  attn_kernel<<<dim3(16, 32, 2), dim3(512), 0, stream>>>(Qb, Kb, VTb, fcos, fsin, AOb);

  gemm256<1><<<dim3(20, 16), dim3(512), 0, stream>>>(AOb, wob, out, 4096, 5120, 4096);
}

// Round 27
// 723.418 us; speedup vs baseline: 1.0022x; 1.0022x over previous
//
#include <hip/hip_runtime.h>

// SelfAttention: x[2,2048,5120] -> QKV proj -> RoPE -> causal GQA attention -> out proj
// All matmuls in bf16 MFMA (16x16x32), f32 accum. Tolerance is bf16-grade (0.148 absmax).
// FINAL: proven configuration (724 us, absmax 0.039, reproduced 10x: r14/17/19-26).
// Attn LDS layout is load-bearing: DO NOT modify P_lds/Ks/Vs geometry (occupancy
// experiments raced). cvt5 merge regressed (r18); separate wo convert is faster.

typedef unsigned short u16;
typedef __bf16 bf16x8 __attribute__((ext_vector_type(8)));
typedef __bf16 bf16x4 __attribute__((ext_vector_type(4)));
typedef float f32x4 __attribute__((ext_vector_type(4)));

__device__ __forceinline__ u16 f2bf(float f) {
  unsigned u = __builtin_bit_cast(unsigned, f);
  u += 0x7fff + ((u >> 16) & 1);   // RNE
  return (u16)(u >> 16);
}
__device__ __forceinline__ float bf2f(u16 h) {
  unsigned u = ((unsigned)h) << 16;
  return __builtin_bit_cast(float, u);
}

__device__ __forceinline__ float exp2_hw(float x) {
#if __has_builtin(__builtin_amdgcn_exp2f)
  return __builtin_amdgcn_exp2f(x);   // v_exp_f32: D = 2^S0
#else
  return __expf(x * 0.6931471805599453f);
#endif
}

__device__ __forceinline__ void gload_lds16(const u16* g, u16* lds) {
  __builtin_amdgcn_global_load_lds(
      (const __attribute__((address_space(1))) void*)g,
      (__attribute__((address_space(3))) void*)lds, 16, 0, 0);
}

__device__ __forceinline__ f32x4 mfma16(bf16x8 a, bf16x8 b, f32x4 c) {
  return __builtin_amdgcn_mfma_f32_16x16x32_bf16(a, b, c, 0, 0, 0);
}

#define VMW(N) asm volatile("s_waitcnt vmcnt(" #N ")" ::: "memory")
#define BAR()  __builtin_amdgcn_s_barrier()

// ---------------- f32 -> bf16 bulk convert (single, 4 segments) ----------------
__global__ __launch_bounds__(256) void cvt4_kernel(const float4* __restrict__ s0,
                                                   const float4* __restrict__ s1,
                                                   const float4* __restrict__ s2,
                                                   const float4* __restrict__ s3,
                                                   uint2* __restrict__ d0,
                                                   uint2* __restrict__ d1,
                                                   uint2* __restrict__ d2,
                                                   uint2* __restrict__ d3,
                                                   int n0, int n1, int n2, int n3) {
  int total = n0 + n1 + n2 + n3;
  for (int i = blockIdx.x * blockDim.x + threadIdx.x; i < total;
       i += gridDim.x * blockDim.x) {
    const float4* s; uint2* d; int j = i;
    if (j < n0) { s = s0; d = d0; }
    else if ((j -= n0) < n1) { s = s1; d = d1; }
    else if ((j -= n1) < n2) { s = s2; d = d2; }
    else { j -= n2; s = s3; d = d3; }
    float4 v = s[j];
    d[j] = make_uint2((unsigned)f2bf(v.x) | ((unsigned)f2bf(v.y) << 16),
                      (unsigned)f2bf(v.z) | ((unsigned)f2bf(v.w) << 16));
  }
}

// ---------------- f32 -> bf16 bulk convert (single segment, for wo) ------------
__global__ __launch_bounds__(256) void cvt_kernel(const float4* __restrict__ in,
                                                  uint2* __restrict__ out, int n4) {
  int i = blockIdx.x * blockDim.x + threadIdx.x;
  if (i >= n4) return;
  float4 v = in[i];
  unsigned lo = (unsigned)f2bf(v.x) | ((unsigned)f2bf(v.y) << 16);
  unsigned hi = (unsigned)f2bf(v.z) | ((unsigned)f2bf(v.w) << 16);
  out[i] = make_uint2(lo, hi);
}

// ---------------- RoPE in-place on bf16 [*, nheads, 64 pairs] ----------------
__global__ __launch_bounds__(256) void rope_kernel(u16* __restrict__ t,
                                                   const float* __restrict__ fcos,
                                                   const float* __restrict__ fsin,
                                                   int hsh, float scale, int total) {
  int idx = blockIdx.x * blockDim.x + threadIdx.x;
  if (idx >= total) return;
  int j = idx & 63;
  int s = (idx >> (6 + hsh)) & 2047;
  float c = fcos[s * 64 + j], sn = fsin[s * 64 + j];
  unsigned* p = (unsigned*)(t + (size_t)idx * 2);
  unsigned v = *p;
  float tr = bf2f((u16)(v & 0xffffu)), ti = bf2f((u16)(v >> 16));
  float orr = (tr * c - ti * sn) * scale;
  float oi  = (tr * sn + ti * c) * scale;
  *p = (unsigned)f2bf(orr) | ((unsigned)f2bf(oi) << 16);
}

// ---------------- bf16 NT GEMM 128x128 ----------------
// MODE 0: bf16 C[M][N]; MODE 2: transposed V store; MODE 3: merged K|V projection
// (B = [wk;wv] contiguous, N=2048; gn<1024 -> K stride 1024, else VT at +4Mi elems).
template <int MODE>
__global__ __launch_bounds__(256) void gemm_bt(const u16* __restrict__ A,
                                               const u16* __restrict__ B,
                                               void* __restrict__ Cout,
                                               int M, int N, int K) {
  __shared__ u16 As[8192];  // [128][64] bf16, chunk c (16B) of row r stored at c^(r&7)
  __shared__ u16 Bs[8192];
  const int tid = threadIdx.x;
  const int lane = tid & 63, wave = tid >> 6;
  const int wm = wave >> 1, wn = wave & 1;
  int gx = gridDim.x, gy = gridDim.y, nwg = gx * gy;
  int orig = blockIdx.y * gx + blockIdx.x;
  int mb, nb;
  if ((gx & 1) == 0 && (gy & 3) == 0 && (nwg & 7) == 0) {
    // XCDs arranged 4 (m) x 2 (n); per-XCD tile (gy/4) x (gx/2) blocks
    int x = orig & 7, idx = orig >> 3;
    int hy = gy >> 2, qx = gx >> 1;
    mb = (x >> 1) * hy + (idx % hy);
    nb = (x & 1) * qx + (idx / hy);
  } else {
    mb = orig / gx; nb = orig % gx;
  }
  const int m0 = mb * 128, n0 = nb * 128;
  const int lc = lane & 15, lg = lane >> 4;

  f32x4 acc[4][4] = {};
  const int sr = tid >> 3, sc = tid & 7;

  for (int kt = 0; kt < K; kt += 64) {
    __syncthreads();
#pragma unroll
    for (int q = 0; q < 4; ++q) {
      int r = q * 32 + sr;
      int cc = sc ^ (r & 7);
      gload_lds16(A + (size_t)(m0 + r) * K + kt + cc * 8, &As[q * 2048 + tid * 8]);
      gload_lds16(B + (size_t)(n0 + r) * K + kt + cc * 8, &Bs[q * 2048 + tid * 8]);
    }
    __syncthreads();
#pragma unroll
    for (int ks = 0; ks < 2; ++ks) {
      bf16x8 af[4], bfr[4];
#pragma unroll
      for (int m = 0; m < 4; ++m) {
        int r = wm * 64 + m * 16 + lc;
        int gc = ks * 4 + lg;
        af[m] = *(const bf16x8*)&As[r * 64 + ((gc ^ (r & 7)) * 8)];
      }
#pragma unroll
      for (int n = 0; n < 4; ++n) {
        int r = wn * 64 + n * 16 + lc;
        int gc = ks * 4 + lg;
        bfr[n] = *(const bf16x8*)&Bs[r * 64 + ((gc ^ (r & 7)) * 8)];
      }
#pragma unroll
      for (int m = 0; m < 4; ++m)
#pragma unroll
        for (int n = 0; n < 4; ++n)
          acc[m][n] = mfma16(af[m], bfr[n], acc[m][n]);
    }
  }

  // epilogue: C/D layout col=lane&15, row=(lane>>4)*4+i  [m89-verified]
#pragma unroll
  for (int m = 0; m < 4; ++m) {
#pragma unroll
    for (int n = 0; n < 4; ++n) {
#pragma unroll
      for (int i = 0; i < 4; ++i) {
        int gm = m0 + wm * 64 + m * 16 + lg * 4 + i;
        int gn = n0 + wn * 64 + n * 16 + lc;
        float v = acc[m][n][i];
        if (MODE == 0) {
          ((u16*)Cout)[(size_t)gm * N + gn] = f2bf(v);
        } else if (MODE == 2) {
          size_t addr = ((size_t)((gm >> 11) * 8 + (gn >> 7)) * 128 + (gn & 127)) * 2048 +
                        (gm & 2047);
          ((u16*)Cout)[addr] = f2bf(v);
        } else {  // MODE 3: merged K|V
          if (gn < 1024) {
            ((u16*)Cout)[(size_t)gm * 1024 + gn] = f2bf(v);
          } else {
            int gnv = gn - 1024;
            size_t addr = 4194304ull +
                          ((size_t)((gm >> 11) * 8 + (gnv >> 7)) * 128 + (gnv & 127)) * 2048 +
                          (gm & 2047);
            ((u16*)Cout)[addr] = f2bf(v);
          }
        }
      }
    }
  }
}

// ---------------- bf16 NT GEMM 256x256, 4-phase READ-AHEAD pipeline ----------
// (round-14 version — 219 us / ~785 TF, MfmaUtil 33.5%)
template <int OUT_F32>
__global__ __launch_bounds__(512, 2) void gemm256(const u16* __restrict__ A,
                                                  const u16* __restrict__ B,
                                                  void* __restrict__ Cout,
                                                  int M, int N, int K) {
  __shared__ u16 lds[2][2][2][8192];  // [buf][A=0/B=1][half][128*64]
  __shared__ u16 dummy[4096];
  const int tid = threadIdx.x, lane = tid & 63, wave = tid >> 6;
  const int wm = wave >> 2;            // A half (M)
  const int wn = wave & 3;             // N quarter
  const int lc = lane & 15, lg = lane >> 4;
  const int bh = wn >> 1;              // B half this wave reads
  const int bs64 = (wn & 1) * 64;      // row slice within B half
  const int str = tid >> 3, ssc = tid & 7;

  int gx = gridDim.x, gy = gridDim.y;
  int orig = blockIdx.y * gx + blockIdx.x;
  int mb, nb;
  if ((gx & 3) == 0 && (gy & 1) == 0) {
    // XCDs arranged 2 (m) x 4 (n); per-XCD tile (gy/2) x (gx/4) blocks
    int x = orig & 7, idx = orig >> 3;
    int hy = gy >> 1, qx = gx >> 2;
    mb = (x >> 2) * hy + (idx % hy);
    nb = (x & 3) * qx + (idx / hy);
  } else {
    mb = orig / gx; nb = orig % gx;
  }
  const int m0 = mb * 256, n0 = nb * 256;

  auto stageA = [&](int buf, int kcol, int r0, bool real) {
    int r = r0 + str, cc = ssc ^ (r & 7);
    const u16* s = A + (size_t)(m0 + r) * K + kcol + cc * 8;
    u16* d0 = real ? &lds[buf][0][0][r0 * 64] : dummy;
    u16* d1 = real ? &lds[buf][0][1][r0 * 64] : dummy;
    gload_lds16(s, d0 + tid * 8);
    gload_lds16(s + (size_t)128 * K, d1 + tid * 8);
  };
  auto stageB = [&](int buf, int kcol, int half, bool real) {
    int r = str, cc = ssc ^ (r & 7);
    int r2 = 64 + str, cc2 = ssc ^ (r2 & 7);
    const u16* s = B + (size_t)(n0 + half * 128) * K + kcol;
    u16* d0 = real ? &lds[buf][1][half][0] : dummy;
    u16* d1 = real ? &lds[buf][1][half][4096] : dummy;
    gload_lds16(s + (size_t)r * K + cc * 8, d0 + tid * 8);
    gload_lds16(s + (size_t)r2 * K + cc2 * 8, d1 + tid * 8);
  };

  f32x4 acc[8][4] = {};
  bf16x8 afk[4][2], bfk[4][2];

  const int nk = K >> 6;
  stageB(0, 0, 0, true);
  stageA(0, 0, 0, true);
  stageB(0, 0, 1, true);
  stageA(0, 0, 64, true);
  stageB(1, 64, 0, true);
  stageA(1, 64, 0, true);
  VMW(6);
  BAR();
  {  // preload af_lo(0), bfv01(0)
    const u16* Ab = &lds[0][0][wm][0];
    const u16* Bb = &lds[0][1][bh][0];
#pragma unroll
    for (int m = 0; m < 4; ++m)
#pragma unroll
      for (int kg = 0; kg < 2; ++kg) {
        int r = m * 16 + lc;
        afk[m][kg] = *(const bf16x8*)&Ab[r * 64 + (((kg * 4 + lg) ^ (r & 7)) * 8)];
      }
#pragma unroll
    for (int n = 0; n < 2; ++n)
#pragma unroll
      for (int kg = 0; kg < 2; ++kg) {
        int r = bs64 + n * 16 + lc;
        bfk[n][kg] = *(const bf16x8*)&Bb[r * 64 + (((kg * 4 + lg) ^ (r & 7)) * 8)];
      }
  }

  for (int t = 0; t < nk; ++t) {
    const int c = t & 1;
    const int t1 = t + 1, t2 = t + 2;
    const int kc1 = (t1 < nk ? t1 : nk - 1) << 6;
    const int kc2 = (t2 < nk ? t2 : nk - 1) << 6;
    const bool h1 = t1 < nk, h2 = t2 < nk;
    const u16* Ab = &lds[c][0][wm][0];
    const u16* Bb = &lds[c][1][bh][0];
    const u16* Abn = &lds[c ^ 1][0][wm][0];
    const u16* Bbn = &lds[c ^ 1][1][bh][0];

    // ---- p1: MFMA m0-3 x n0-1 ; read bfv23(t) ----
    stageB(t1 & 1, kc1, 1, h1);      // B1(t+1)
    BAR();
    __builtin_amdgcn_s_setprio(1);
#pragma unroll
    for (int m = 0; m < 4; ++m)
#pragma unroll
      for (int n = 0; n < 2; ++n)
#pragma unroll
        for (int kg = 0; kg < 2; ++kg)
          acc[m][n] = mfma16(afk[m][kg], bfk[n][kg], acc[m][n]);
    __builtin_amdgcn_s_setprio(0);
#pragma unroll
    for (int n = 2; n < 4; ++n)
#pragma unroll
      for (int kg = 0; kg < 2; ++kg) {
        int r = bs64 + n * 16 + lc;
        bfk[n][kg] = *(const bf16x8*)&Bb[r * 64 + (((kg * 4 + lg) ^ (r & 7)) * 8)];
      }
    BAR();

    // ---- p2: MFMA m0-3 x n2-3 ; read af_hi(t) ----
    VMW(6);                          // drains Ah(t) (4-phase slack)
    stageA(t1 & 1, kc1, 64, h1);     // Ah(t+1)
    BAR();
    __builtin_amdgcn_s_setprio(1);
#pragma unroll
    for (int m = 0; m < 4; ++m)
#pragma unroll
      for (int n = 2; n < 4; ++n)
#pragma unroll
        for (int kg = 0; kg < 2; ++kg)
          acc[m][n] = mfma16(afk[m][kg], bfk[n][kg], acc[m][n]);
    __builtin_amdgcn_s_setprio(0);
#pragma unroll
    for (int m = 0; m < 4; ++m)
#pragma unroll
      for (int kg = 0; kg < 2; ++kg) {
        int r = 64 + m * 16 + lc;
        afk[m][kg] = *(const bf16x8*)&Ab[r * 64 + (((kg * 4 + lg) ^ (r & 7)) * 8)];
      }
    BAR();

    // ---- p3: MFMA m4-7 x n0-1 ; read bfv01(t+1) from next buf ----
    VMW(2);                          // drains B0(t+1), Al(t+1), B1(t+1)
    stageB(t2 & 1, kc2, 0, h2);      // B0(t+2)
    BAR();
    __builtin_amdgcn_s_setprio(1);
#pragma unroll
    for (int m = 0; m < 4; ++m)
#pragma unroll
      for (int n = 0; n < 2; ++n)
#pragma unroll
        for (int kg = 0; kg < 2; ++kg)
          acc[4 + m][n] = mfma16(afk[m][kg], bfk[n][kg], acc[4 + m][n]);
    __builtin_amdgcn_s_setprio(0);
#pragma unroll
    for (int n = 0; n < 2; ++n)
#pragma unroll
      for (int kg = 0; kg < 2; ++kg) {
        int r = bs64 + n * 16 + lc;
        bfk[n][kg] = *(const bf16x8*)&Bbn[r * 64 + (((kg * 4 + lg) ^ (r & 7)) * 8)];
      }
    BAR();

    // ---- p4: MFMA m4-7 x n2-3 ; read af_lo(t+1) from next buf ----
    stageA(t2 & 1, kc2, 0, h2);      // Al(t+2)
    BAR();
    __builtin_amdgcn_s_setprio(1);
#pragma unroll
    for (int m = 0; m < 4; ++m)
#pragma unroll
      for (int n = 2; n < 4; ++n)
#pragma unroll
        for (int kg = 0; kg < 2; ++kg)
          acc[4 + m][n] = mfma16(afk[m][kg], bfk[n][kg], acc[4 + m][n]);
    __builtin_amdgcn_s_setprio(0);
#pragma unroll
    for (int m = 0; m < 4; ++m)
#pragma unroll
      for (int kg = 0; kg < 2; ++kg) {
        int r = m * 16 + lc;
        afk[m][kg] = *(const bf16x8*)&Abn[r * 64 + (((kg * 4 + lg) ^ (r & 7)) * 8)];
      }
    BAR();
  }

  // epilogue: C/D layout col=lane&15, row=(lane>>4)*4+i
#pragma unroll
  for (int m = 0; m < 8; ++m) {
#pragma unroll
    for (int n = 0; n < 4; ++n) {
#pragma unroll
      for (int i = 0; i < 4; ++i) {
        int gm = m0 + wm * 128 + m * 16 + lg * 4 + i;
        int gn = n0 + wn * 64 + n * 16 + lc;
        float v = acc[m][n][i];
        if (OUT_F32) ((float*)Cout)[(size_t)gm * N + gn] = v;
        else         ((u16*)Cout)[(size_t)gm * N + gn] = f2bf(v);
      }
    }
  }
}

// ---------------- causal GQA flash attention (v5: QBLK=128, fused Q-RoPE) -----
// Proven kernel (absmax 0.039, stable across timed replays, 10 reproductions).
// grid (S/128, HQ, B), 512 thr = 8 waves; P_lds stride 72 — DO NOT CHANGE.
__global__ __launch_bounds__(512) void attn_kernel(const u16* __restrict__ Q,
                                                   const u16* __restrict__ Kg,
                                                   const u16* __restrict__ VT,
                                                   const float* __restrict__ fcos,
                                                   const float* __restrict__ fsin,
                                                   u16* __restrict__ AO) {
  __shared__ u16 Ks[2][8192];        // [kv 64][d 128] per buf, chunk c at c^(r&15)
  __shared__ u16 Vs[2][8192];        // [d 128][kv 64] per buf, chunk c at c^(r&7)
  __shared__ u16 P_lds[8][16 * 72];  // per-wave P [q 16][kv 64], stride 72
  const int tid = threadIdx.x, lane = tid & 63, w = tid >> 6;
  const int qt = (int)gridDim.x - 1 - (int)blockIdx.x;  // heavy blocks first
  const int h = blockIdx.y, b = blockIdx.z;
  const int hkv = h >> 2;
  const int q0 = qt * 128;
  const int lc = lane & 15, lg = lane >> 4;

  // Q fragments + in-register RoPE (+ exp2 scale). Pair j = ks*16 + lg*4 + p.
  const float qs = 0.12751743558818574f;  // log2(e)/sqrt(128)
  const int srow = q0 + w * 16 + lc;      // this lane's q row (within batch)
  bf16x8 qf[4];
  {
    const size_t qrow = ((size_t)(b * 2048 + srow) * 32 + h) * 128;
#pragma unroll
    for (int ks = 0; ks < 4; ++ks) {
      bf16x8 raw = *(const bf16x8*)&Q[qrow + ks * 32 + lg * 8];
      float4 c4 = *(const float4*)&fcos[srow * 64 + ks * 16 + lg * 4];
      float4 s4 = *(const float4*)&fsin[srow * 64 + ks * 16 + lg * 4];
#pragma unroll
      for (int p = 0; p < 4; ++p) {
        float cc = (&c4.x)[p], ss = (&s4.x)[p];
        float tr = (float)raw[2 * p], ti = (float)raw[2 * p + 1];
        qf[ks][2 * p]     = (__bf16)((tr * cc - ti * ss) * qs);
        qf[ks][2 * p + 1] = (__bf16)((tr * ss + ti * cc) * qs);
      }
    }
  }

  f32x4 o[8] = {};
  f32x4 lsum = {0.f, 0.f, 0.f, 0.f};

  const int nsteps = 2 * qt + 2;
  const size_t kpanel = ((size_t)b * 2048 * 8 + hkv) * 128;
  const size_t vpanel = ((size_t)(b * 8 + hkv) * 128) * 2048;

  auto stage = [&](int buf, int step) {
    const int kv0 = step * 64;
#pragma unroll
    for (int p = 0; p < 2; ++p) {  // K tile: 64 rows x 256B, 512 thr
      int r = p * 32 + (tid >> 4);
      int cc = (tid & 15) ^ (r & 15);
      gload_lds16(Kg + kpanel + (size_t)(kv0 + r) * 1024 + cc * 8,
                  &Ks[buf][p * 4096 + tid * 8]);
    }
#pragma unroll
    for (int p = 0; p < 2; ++p) {  // VT tile: 128 rows x 128B
      int r = p * 64 + (tid >> 3);
      int cc = (tid & 7) ^ (r & 7);
      gload_lds16(VT + vpanel + (size_t)r * 2048 + kv0 + cc * 8,
                  &Vs[buf][p * 4096 + tid * 8]);
    }
  };

  stage(0, 0);

  for (int step = 0; step < nsteps; ++step) {
    const int kv0 = step * 64;
    __syncthreads();
    if (step + 1 < nsteps) stage((step + 1) & 1, step + 1);
    const u16* kb = Ks[step & 1];
    const u16* vb = Vs[step & 1];

    f32x4 s[4];
#pragma unroll
    for (int nf = 0; nf < 4; ++nf) s[nf] = f32x4{0.f, 0.f, 0.f, 0.f};
    __builtin_amdgcn_s_setprio(1);
#pragma unroll
    for (int ks = 0; ks < 4; ++ks) {
#pragma unroll
      for (int nf = 0; nf < 4; ++nf) {
        int r = nf * 16 + lc;
        int gc = ks * 4 + lg;
        bf16x8 kf = *(const bf16x8*)&kb[r * 128 + ((gc ^ (r & 15)) * 8)];
        s[nf] = mfma16(kf, qf[ks], s[nf]);  // swapped: S[kv][q=lc]
      }
    }
    __builtin_amdgcn_s_setprio(0);

    if (step >= 2 * qt) {  // diagonal region (last two steps)
      int q = srow;
#pragma unroll
      for (int nf = 0; nf < 4; ++nf) {
#pragma unroll
        for (int i = 0; i < 4; ++i) {
          int kv = kv0 + nf * 16 + lg * 4 + i;
          if (kv > q) s[nf][i] = -1e30f;
        }
      }
    }

#pragma unroll
    for (int nf = 0; nf < 4; ++nf) {
#pragma unroll
      for (int i = 0; i < 4; ++i) s[nf][i] = exp2_hw(s[nf][i]);
      lsum += s[nf];
      bf16x4 pw = {(__bf16)s[nf][0], (__bf16)s[nf][1], (__bf16)s[nf][2], (__bf16)s[nf][3]};
      *(bf16x4*)&P_lds[w][lc * 72 + nf * 16 + lg * 4] = pw;
    }
    asm volatile("s_waitcnt lgkmcnt(0)" ::: "memory");
    __builtin_amdgcn_sched_barrier(0);

    bf16x8 pa[2];
#pragma unroll
    for (int ksv = 0; ksv < 2; ++ksv)
      pa[ksv] = *(const bf16x8*)&P_lds[w][lc * 72 + ksv * 32 + lg * 8];

    __builtin_amdgcn_s_setprio(1);
#pragma unroll
    for (int nfd = 0; nfd < 8; ++nfd) {
#pragma unroll
      for (int ksv = 0; ksv < 2; ++ksv) {
        int r = nfd * 16 + lc;
        int gc = ksv * 4 + lg;
        bf16x8 vf = *(const bf16x8*)&vb[r * 64 + ((gc ^ (r & 7)) * 8)];
        o[nfd] = mfma16(pa[ksv], vf, o[nfd]);
      }
    }
    __builtin_amdgcn_s_setprio(0);
  }

  float t = lsum[0] + lsum[1] + lsum[2] + lsum[3];
  t += __shfl_xor(t, 16, 64);
  t += __shfl_xor(t, 32, 64);
  float linv[4];
#pragma unroll
  for (int i = 0; i < 4; ++i) linv[i] = 1.0f / __shfl(t, lg * 4 + i, 64);

#pragma unroll
  for (int nfd = 0; nfd < 8; ++nfd)
#pragma unroll
    for (int i = 0; i < 4; ++i) {
      int row = q0 + w * 16 + lg * 4 + i;
      AO[((size_t)(b * 2048 + row) * 32 + h) * 128 + nfd * 16 + lc] =
          f2bf(o[nfd][i] * linv[i]);
    }
}

extern "C" void kernel_launch(void* const* d_in, const int* in_sizes, int n_in,
                              void* d_out, int out_size, void* d_ws, size_t ws_size,
                              hipStream_t stream) {
  const float* x    = (const float*)d_in[0];
  const float* fcos = (const float*)d_in[1];
  const float* fsin = (const float*)d_in[2];
  const float* wq   = (const float*)d_in[3];
  const float* wk   = (const float*)d_in[4];
  const float* wv   = (const float*)d_in[5];
  const float* wo   = (const float*)d_in[6];
  float* out = (float*)d_out;

  char* ws = (char*)d_ws;
  u16* xb  = (u16*)(ws + 0);             // x bf16  -> later AO
  u16* wqb = (u16*)(ws + 41943040ull);   // wq bf16 -> later wo bf16
  u16* wkb = (u16*)(ws + 83886080ull);   // [wk; wv] CONTIGUOUS (wkv = [2048][5120])
  u16* wvb = (u16*)(ws + 94371840ull);
  u16* Qb  = (u16*)(ws + 104857600ull);
  u16* Kb  = (u16*)(ws + 138412032ull);  // [Kb; VTb] CONTIGUOUS (VT at +4Mi elems)
  u16* VTb = (u16*)(ws + 146800640ull);  // total 155,189,248 B
  u16* AOb = xb;
  u16* wob = wqb;

  // one launch converts x, wq, wk, wv (wo waits: its dst aliases wq's slot)
  cvt4_kernel<<<dim3(2048), dim3(256), 0, stream>>>(
      (const float4*)x, (const float4*)wq, (const float4*)wk, (const float4*)wv,
      (uint2*)xb, (uint2*)wqb, (uint2*)wkb, (uint2*)wvb,
      2 * 2048 * 5120 / 4, 4096 * 5120 / 4, 1024 * 5120 / 4, 1024 * 5120 / 4);

  dim3 blk(256);
  gemm256<0><<<dim3(16, 16), dim3(512), 0, stream>>>(xb, wqb, Qb, 4096, 4096, 5120);
  // merged K+V projection: gemm_bt with B=[wk;wv], N=2048; MODE 3 epilogue
  gemm_bt<3><<<dim3(16, 32), blk, 0, stream>>>(xb, wkb, Kb, 4096, 2048, 5120);

  cvt_kernel<<<dim3(5242880 / 256), blk, 0, stream>>>((const float4*)wo, (uint2*)wob,
                                                      5242880);  // wq dead; reuse slot

  // K-RoPE (proven kernel); Q-RoPE (+ scale) is fused into attn_kernel.
  rope_kernel<<<dim3(2097152 / 256), blk, 0, stream>>>(Kb, fcos, fsin, 3, 1.0f, 2097152);

  attn_kernel<<<dim3(16, 32, 2), dim3(512), 0, stream>>>(Qb, Kb, VTb, fcos, fsin, AOb);

  gemm256<1><<<dim3(20, 16), dim3(512), 0, stream>>>(AOb, wob, out, 4096, 5120, 4096);
}

// Round 28
// 723.334 us; speedup vs baseline: 1.0023x; 1.0001x over previous
//
#include <hip/hip_runtime.h>

// SelfAttention: x[2,2048,5120] -> QKV proj -> RoPE -> causal GQA attention -> out proj
// All matmuls in bf16 MFMA (16x16x32), f32 accum. Tolerance is bf16-grade (0.148 absmax).
// FINAL: proven configuration (724 us, absmax 0.039, reproduced 11x: r14/17/19-27).
// Attn LDS layout is load-bearing: DO NOT modify P_lds/Ks/Vs geometry (occupancy
// experiments raced). cvt5 merge regressed (r18); separate wo convert is faster.

typedef unsigned short u16;
typedef __bf16 bf16x8 __attribute__((ext_vector_type(8)));
typedef __bf16 bf16x4 __attribute__((ext_vector_type(4)));
typedef float f32x4 __attribute__((ext_vector_type(4)));

__device__ __forceinline__ u16 f2bf(float f) {
  unsigned u = __builtin_bit_cast(unsigned, f);
  u += 0x7fff + ((u >> 16) & 1);   // RNE
  return (u16)(u >> 16);
}
__device__ __forceinline__ float bf2f(u16 h) {
  unsigned u = ((unsigned)h) << 16;
  return __builtin_bit_cast(float, u);
}

__device__ __forceinline__ float exp2_hw(float x) {
#if __has_builtin(__builtin_amdgcn_exp2f)
  return __builtin_amdgcn_exp2f(x);   // v_exp_f32: D = 2^S0
#else
  return __expf(x * 0.6931471805599453f);
#endif
}

__device__ __forceinline__ void gload_lds16(const u16* g, u16* lds) {
  __builtin_amdgcn_global_load_lds(
      (const __attribute__((address_space(1))) void*)g,
      (__attribute__((address_space(3))) void*)lds, 16, 0, 0);
}

__device__ __forceinline__ f32x4 mfma16(bf16x8 a, bf16x8 b, f32x4 c) {
  return __builtin_amdgcn_mfma_f32_16x16x32_bf16(a, b, c, 0, 0, 0);
}

#define VMW(N) asm volatile("s_waitcnt vmcnt(" #N ")" ::: "memory")
#define BAR()  __builtin_amdgcn_s_barrier()

// ---------------- f32 -> bf16 bulk convert (single, 4 segments) ----------------
__global__ __launch_bounds__(256) void cvt4_kernel(const float4* __restrict__ s0,
                                                   const float4* __restrict__ s1,
                                                   const float4* __restrict__ s2,
                                                   const float4* __restrict__ s3,
                                                   uint2* __restrict__ d0,
                                                   uint2* __restrict__ d1,
                                                   uint2* __restrict__ d2,
                                                   uint2* __restrict__ d3,
                                                   int n0, int n1, int n2, int n3) {
  int total = n0 + n1 + n2 + n3;
  for (int i = blockIdx.x * blockDim.x + threadIdx.x; i < total;
       i += gridDim.x * blockDim.x) {
    const float4* s; uint2* d; int j = i;
    if (j < n0) { s = s0; d = d0; }
    else if ((j -= n0) < n1) { s = s1; d = d1; }
    else if ((j -= n1) < n2) { s = s2; d = d2; }
    else { j -= n2; s = s3; d = d3; }
    float4 v = s[j];
    d[j] = make_uint2((unsigned)f2bf(v.x) | ((unsigned)f2bf(v.y) << 16),
                      (unsigned)f2bf(v.z) | ((unsigned)f2bf(v.w) << 16));
  }
}

// ---------------- f32 -> bf16 bulk convert (single segment, for wo) ------------
__global__ __launch_bounds__(256) void cvt_kernel(const float4* __restrict__ in,
                                                  uint2* __restrict__ out, int n4) {
  int i = blockIdx.x * blockDim.x + threadIdx.x;
  if (i >= n4) return;
  float4 v = in[i];
  unsigned lo = (unsigned)f2bf(v.x) | ((unsigned)f2bf(v.y) << 16);
  unsigned hi = (unsigned)f2bf(v.z) | ((unsigned)f2bf(v.w) << 16);
  out[i] = make_uint2(lo, hi);
}

// ---------------- RoPE in-place on bf16 [*, nheads, 64 pairs] ----------------
__global__ __launch_bounds__(256) void rope_kernel(u16* __restrict__ t,
                                                   const float* __restrict__ fcos,
                                                   const float* __restrict__ fsin,
                                                   int hsh, float scale, int total) {
  int idx = blockIdx.x * blockDim.x + threadIdx.x;
  if (idx >= total) return;
  int j = idx & 63;
  int s = (idx >> (6 + hsh)) & 2047;
  float c = fcos[s * 64 + j], sn = fsin[s * 64 + j];
  unsigned* p = (unsigned*)(t + (size_t)idx * 2);
  unsigned v = *p;
  float tr = bf2f((u16)(v & 0xffffu)), ti = bf2f((u16)(v >> 16));
  float orr = (tr * c - ti * sn) * scale;
  float oi  = (tr * sn + ti * c) * scale;
  *p = (unsigned)f2bf(orr) | ((unsigned)f2bf(oi) << 16);
}

// ---------------- bf16 NT GEMM 128x128 ----------------
// MODE 0: bf16 C[M][N]; MODE 2: transposed V store; MODE 3: merged K|V projection
// (B = [wk;wv] contiguous, N=2048; gn<1024 -> K stride 1024, else VT at +4Mi elems).
template <int MODE>
__global__ __launch_bounds__(256) void gemm_bt(const u16* __restrict__ A,
                                               const u16* __restrict__ B,
                                               void* __restrict__ Cout,
                                               int M, int N, int K) {
  __shared__ u16 As[8192];  // [128][64] bf16, chunk c (16B) of row r stored at c^(r&7)
  __shared__ u16 Bs[8192];
  const int tid = threadIdx.x;
  const int lane = tid & 63, wave = tid >> 6;
  const int wm = wave >> 1, wn = wave & 1;
  int gx = gridDim.x, gy = gridDim.y, nwg = gx * gy;
  int orig = blockIdx.y * gx + blockIdx.x;
  int mb, nb;
  if ((gx & 1) == 0 && (gy & 3) == 0 && (nwg & 7) == 0) {
    // XCDs arranged 4 (m) x 2 (n); per-XCD tile (gy/4) x (gx/2) blocks
    int x = orig & 7, idx = orig >> 3;
    int hy = gy >> 2, qx = gx >> 1;
    mb = (x >> 1) * hy + (idx % hy);
    nb = (x & 1) * qx + (idx / hy);
  } else {
    mb = orig / gx; nb = orig % gx;
  }
  const int m0 = mb * 128, n0 = nb * 128;
  const int lc = lane & 15, lg = lane >> 4;

  f32x4 acc[4][4] = {};
  const int sr = tid >> 3, sc = tid & 7;

  for (int kt = 0; kt < K; kt += 64) {
    __syncthreads();
#pragma unroll
    for (int q = 0; q < 4; ++q) {
      int r = q * 32 + sr;
      int cc = sc ^ (r & 7);
      gload_lds16(A + (size_t)(m0 + r) * K + kt + cc * 8, &As[q * 2048 + tid * 8]);
      gload_lds16(B + (size_t)(n0 + r) * K + kt + cc * 8, &Bs[q * 2048 + tid * 8]);
    }
    __syncthreads();
#pragma unroll
    for (int ks = 0; ks < 2; ++ks) {
      bf16x8 af[4], bfr[4];
#pragma unroll
      for (int m = 0; m < 4; ++m) {
        int r = wm * 64 + m * 16 + lc;
        int gc = ks * 4 + lg;
        af[m] = *(const bf16x8*)&As[r * 64 + ((gc ^ (r & 7)) * 8)];
      }
#pragma unroll
      for (int n = 0; n < 4; ++n) {
        int r = wn * 64 + n * 16 + lc;
        int gc = ks * 4 + lg;
        bfr[n] = *(const bf16x8*)&Bs[r * 64 + ((gc ^ (r & 7)) * 8)];
      }
#pragma unroll
      for (int m = 0; m < 4; ++m)
#pragma unroll
        for (int n = 0; n < 4; ++n)
          acc[m][n] = mfma16(af[m], bfr[n], acc[m][n]);
    }
  }

  // epilogue: C/D layout col=lane&15, row=(lane>>4)*4+i  [m89-verified]
#pragma unroll
  for (int m = 0; m < 4; ++m) {
#pragma unroll
    for (int n = 0; n < 4; ++n) {
#pragma unroll
      for (int i = 0; i < 4; ++i) {
        int gm = m0 + wm * 64 + m * 16 + lg * 4 + i;
        int gn = n0 + wn * 64 + n * 16 + lc;
        float v = acc[m][n][i];
        if (MODE == 0) {
          ((u16*)Cout)[(size_t)gm * N + gn] = f2bf(v);
        } else if (MODE == 2) {
          size_t addr = ((size_t)((gm >> 11) * 8 + (gn >> 7)) * 128 + (gn & 127)) * 2048 +
                        (gm & 2047);
          ((u16*)Cout)[addr] = f2bf(v);
        } else {  // MODE 3: merged K|V
          if (gn < 1024) {
            ((u16*)Cout)[(size_t)gm * 1024 + gn] = f2bf(v);
          } else {
            int gnv = gn - 1024;
            size_t addr = 4194304ull +
                          ((size_t)((gm >> 11) * 8 + (gnv >> 7)) * 128 + (gnv & 127)) * 2048 +
                          (gm & 2047);
            ((u16*)Cout)[addr] = f2bf(v);
          }
        }
      }
    }
  }
}

// ---------------- bf16 NT GEMM 256x256, 4-phase READ-AHEAD pipeline ----------
// (round-14 version — 219 us / ~785 TF, MfmaUtil 33.5%)
template <int OUT_F32>
__global__ __launch_bounds__(512, 2) void gemm256(const u16* __restrict__ A,
                                                  const u16* __restrict__ B,
                                                  void* __restrict__ Cout,
                                                  int M, int N, int K) {
  __shared__ u16 lds[2][2][2][8192];  // [buf][A=0/B=1][half][128*64]
  __shared__ u16 dummy[4096];
  const int tid = threadIdx.x, lane = tid & 63, wave = tid >> 6;
  const int wm = wave >> 2;            // A half (M)
  const int wn = wave & 3;             // N quarter
  const int lc = lane & 15, lg = lane >> 4;
  const int bh = wn >> 1;              // B half this wave reads
  const int bs64 = (wn & 1) * 64;      // row slice within B half
  const int str = tid >> 3, ssc = tid & 7;

  int gx = gridDim.x, gy = gridDim.y;
  int orig = blockIdx.y * gx + blockIdx.x;
  int mb, nb;
  if ((gx & 3) == 0 && (gy & 1) == 0) {
    // XCDs arranged 2 (m) x 4 (n); per-XCD tile (gy/2) x (gx/4) blocks
    int x = orig & 7, idx = orig >> 3;
    int hy = gy >> 1, qx = gx >> 2;
    mb = (x >> 2) * hy + (idx % hy);
    nb = (x & 3) * qx + (idx / hy);
  } else {
    mb = orig / gx; nb = orig % gx;
  }
  const int m0 = mb * 256, n0 = nb * 256;

  auto stageA = [&](int buf, int kcol, int r0, bool real) {
    int r = r0 + str, cc = ssc ^ (r & 7);
    const u16* s = A + (size_t)(m0 + r) * K + kcol + cc * 8;
    u16* d0 = real ? &lds[buf][0][0][r0 * 64] : dummy;
    u16* d1 = real ? &lds[buf][0][1][r0 * 64] : dummy;
    gload_lds16(s, d0 + tid * 8);
    gload_lds16(s + (size_t)128 * K, d1 + tid * 8);
  };
  auto stageB = [&](int buf, int kcol, int half, bool real) {
    int r = str, cc = ssc ^ (r & 7);
    int r2 = 64 + str, cc2 = ssc ^ (r2 & 7);
    const u16* s = B + (size_t)(n0 + half * 128) * K + kcol;
    u16* d0 = real ? &lds[buf][1][half][0] : dummy;
    u16* d1 = real ? &lds[buf][1][half][4096] : dummy;
    gload_lds16(s + (size_t)r * K + cc * 8, d0 + tid * 8);
    gload_lds16(s + (size_t)r2 * K + cc2 * 8, d1 + tid * 8);
  };

  f32x4 acc[8][4] = {};
  bf16x8 afk[4][2], bfk[4][2];

  const int nk = K >> 6;
  stageB(0, 0, 0, true);
  stageA(0, 0, 0, true);
  stageB(0, 0, 1, true);
  stageA(0, 0, 64, true);
  stageB(1, 64, 0, true);
  stageA(1, 64, 0, true);
  VMW(6);
  BAR();
  {  // preload af_lo(0), bfv01(0)
    const u16* Ab = &lds[0][0][wm][0];
    const u16* Bb = &lds[0][1][bh][0];
#pragma unroll
    for (int m = 0; m < 4; ++m)
#pragma unroll
      for (int kg = 0; kg < 2; ++kg) {
        int r = m * 16 + lc;
        afk[m][kg] = *(const bf16x8*)&Ab[r * 64 + (((kg * 4 + lg) ^ (r & 7)) * 8)];
      }
#pragma unroll
    for (int n = 0; n < 2; ++n)
#pragma unroll
      for (int kg = 0; kg < 2; ++kg) {
        int r = bs64 + n * 16 + lc;
        bfk[n][kg] = *(const bf16x8*)&Bb[r * 64 + (((kg * 4 + lg) ^ (r & 7)) * 8)];
      }
  }

  for (int t = 0; t < nk; ++t) {
    const int c = t & 1;
    const int t1 = t + 1, t2 = t + 2;
    const int kc1 = (t1 < nk ? t1 : nk - 1) << 6;
    const int kc2 = (t2 < nk ? t2 : nk - 1) << 6;
    const bool h1 = t1 < nk, h2 = t2 < nk;
    const u16* Ab = &lds[c][0][wm][0];
    const u16* Bb = &lds[c][1][bh][0];
    const u16* Abn = &lds[c ^ 1][0][wm][0];
    const u16* Bbn = &lds[c ^ 1][1][bh][0];

    // ---- p1: MFMA m0-3 x n0-1 ; read bfv23(t) ----
    stageB(t1 & 1, kc1, 1, h1);      // B1(t+1)
    BAR();
    __builtin_amdgcn_s_setprio(1);
#pragma unroll
    for (int m = 0; m < 4; ++m)
#pragma unroll
      for (int n = 0; n < 2; ++n)
#pragma unroll
        for (int kg = 0; kg < 2; ++kg)
          acc[m][n] = mfma16(afk[m][kg], bfk[n][kg], acc[m][n]);
    __builtin_amdgcn_s_setprio(0);
#pragma unroll
    for (int n = 2; n < 4; ++n)
#pragma unroll
      for (int kg = 0; kg < 2; ++kg) {
        int r = bs64 + n * 16 + lc;
        bfk[n][kg] = *(const bf16x8*)&Bb[r * 64 + (((kg * 4 + lg) ^ (r & 7)) * 8)];
      }
    BAR();

    // ---- p2: MFMA m0-3 x n2-3 ; read af_hi(t) ----
    VMW(6);                          // drains Ah(t) (4-phase slack)
    stageA(t1 & 1, kc1, 64, h1);     // Ah(t+1)
    BAR();
    __builtin_amdgcn_s_setprio(1);
#pragma unroll
    for (int m = 0; m < 4; ++m)
#pragma unroll
      for (int n = 2; n < 4; ++n)
#pragma unroll
        for (int kg = 0; kg < 2; ++kg)
          acc[m][n] = mfma16(afk[m][kg], bfk[n][kg], acc[m][n]);
    __builtin_amdgcn_s_setprio(0);
#pragma unroll
    for (int m = 0; m < 4; ++m)
#pragma unroll
      for (int kg = 0; kg < 2; ++kg) {
        int r = 64 + m * 16 + lc;
        afk[m][kg] = *(const bf16x8*)&Ab[r * 64 + (((kg * 4 + lg) ^ (r & 7)) * 8)];
      }
    BAR();

    // ---- p3: MFMA m4-7 x n0-1 ; read bfv01(t+1) from next buf ----
    VMW(2);                          // drains B0(t+1), Al(t+1), B1(t+1)
    stageB(t2 & 1, kc2, 0, h2);      // B0(t+2)
    BAR();
    __builtin_amdgcn_s_setprio(1);
#pragma unroll
    for (int m = 0; m < 4; ++m)
#pragma unroll
      for (int n = 0; n < 2; ++n)
#pragma unroll
        for (int kg = 0; kg < 2; ++kg)
          acc[4 + m][n] = mfma16(afk[m][kg], bfk[n][kg], acc[4 + m][n]);
    __builtin_amdgcn_s_setprio(0);
#pragma unroll
    for (int n = 0; n < 2; ++n)
#pragma unroll
      for (int kg = 0; kg < 2; ++kg) {
        int r = bs64 + n * 16 + lc;
        bfk[n][kg] = *(const bf16x8*)&Bbn[r * 64 + (((kg * 4 + lg) ^ (r & 7)) * 8)];
      }
    BAR();

    // ---- p4: MFMA m4-7 x n2-3 ; read af_lo(t+1) from next buf ----
    stageA(t2 & 1, kc2, 0, h2);      // Al(t+2)
    BAR();
    __builtin_amdgcn_s_setprio(1);
#pragma unroll
    for (int m = 0; m < 4; ++m)
#pragma unroll
      for (int n = 2; n < 4; ++n)
#pragma unroll
        for (int kg = 0; kg < 2; ++kg)
          acc[4 + m][n] = mfma16(afk[m][kg], bfk[n][kg], acc[4 + m][n]);
    __builtin_amdgcn_s_setprio(0);
#pragma unroll
    for (int m = 0; m < 4; ++m)
#pragma unroll
      for (int kg = 0; kg < 2; ++kg) {
        int r = m * 16 + lc;
        afk[m][kg] = *(const bf16x8*)&Abn[r * 64 + (((kg * 4 + lg) ^ (r & 7)) * 8)];
      }
    BAR();
  }

  // epilogue: C/D layout col=lane&15, row=(lane>>4)*4+i
#pragma unroll
  for (int m = 0; m < 8; ++m) {
#pragma unroll
    for (int n = 0; n < 4; ++n) {
#pragma unroll
      for (int i = 0; i < 4; ++i) {
        int gm = m0 + wm * 128 + m * 16 + lg * 4 + i;
        int gn = n0 + wn * 64 + n * 16 + lc;
        float v = acc[m][n][i];
        if (OUT_F32) ((float*)Cout)[(size_t)gm * N + gn] = v;
        else         ((u16*)Cout)[(size_t)gm * N + gn] = f2bf(v);
      }
    }
  }
}

// ---------------- causal GQA flash attention (v5: QBLK=128, fused Q-RoPE) -----
// Proven kernel (absmax 0.039, stable across timed replays, 11 reproductions).
// grid (S/128, HQ, B), 512 thr = 8 waves; P_lds stride 72 — DO NOT CHANGE.
__global__ __launch_bounds__(512) void attn_kernel(const u16* __restrict__ Q,
                                                   const u16* __restrict__ Kg,
                                                   const u16* __restrict__ VT,
                                                   const float* __restrict__ fcos,
                                                   const float* __restrict__ fsin,
                                                   u16* __restrict__ AO) {
  __shared__ u16 Ks[2][8192];        // [kv 64][d 128] per buf, chunk c at c^(r&15)
  __shared__ u16 Vs[2][8192];        // [d 128][kv 64] per buf, chunk c at c^(r&7)
  __shared__ u16 P_lds[8][16 * 72];  // per-wave P [q 16][kv 64], stride 72
  const int tid = threadIdx.x, lane = tid & 63, w = tid >> 6;
  const int qt = (int)gridDim.x - 1 - (int)blockIdx.x;  // heavy blocks first
  const int h = blockIdx.y, b = blockIdx.z;
  const int hkv = h >> 2;
  const int q0 = qt * 128;
  const int lc = lane & 15, lg = lane >> 4;

  // Q fragments + in-register RoPE (+ exp2 scale). Pair j = ks*16 + lg*4 + p.
  const float qs = 0.12751743558818574f;  // log2(e)/sqrt(128)
  const int srow = q0 + w * 16 + lc;      // this lane's q row (within batch)
  bf16x8 qf[4];
  {
    const size_t qrow = ((size_t)(b * 2048 + srow) * 32 + h) * 128;
#pragma unroll
    for (int ks = 0; ks < 4; ++ks) {
      bf16x8 raw = *(const bf16x8*)&Q[qrow + ks * 32 + lg * 8];
      float4 c4 = *(const float4*)&fcos[srow * 64 + ks * 16 + lg * 4];
      float4 s4 = *(const float4*)&fsin[srow * 64 + ks * 16 + lg * 4];
#pragma unroll
      for (int p = 0; p < 4; ++p) {
        float cc = (&c4.x)[p], ss = (&s4.x)[p];
        float tr = (float)raw[2 * p], ti = (float)raw[2 * p + 1];
        qf[ks][2 * p]     = (__bf16)((tr * cc - ti * ss) * qs);
        qf[ks][2 * p + 1] = (__bf16)((tr * ss + ti * cc) * qs);
      }
    }
  }

  f32x4 o[8] = {};
  f32x4 lsum = {0.f, 0.f, 0.f, 0.f};

  const int nsteps = 2 * qt + 2;
  const size_t kpanel = ((size_t)b * 2048 * 8 + hkv) * 128;
  const size_t vpanel = ((size_t)(b * 8 + hkv) * 128) * 2048;

  auto stage = [&](int buf, int step) {
    const int kv0 = step * 64;
#pragma unroll
    for (int p = 0; p < 2; ++p) {  // K tile: 64 rows x 256B, 512 thr
      int r = p * 32 + (tid >> 4);
      int cc = (tid & 15) ^ (r & 15);
      gload_lds16(Kg + kpanel + (size_t)(kv0 + r) * 1024 + cc * 8,
                  &Ks[buf][p * 4096 + tid * 8]);
    }
#pragma unroll
    for (int p = 0; p < 2; ++p) {  // VT tile: 128 rows x 128B
      int r = p * 64 + (tid >> 3);
      int cc = (tid & 7) ^ (r & 7);
      gload_lds16(VT + vpanel + (size_t)r * 2048 + kv0 + cc * 8,
                  &Vs[buf][p * 4096 + tid * 8]);
    }
  };

  stage(0, 0);

  for (int step = 0; step < nsteps; ++step) {
    const int kv0 = step * 64;
    __syncthreads();
    if (step + 1 < nsteps) stage((step + 1) & 1, step + 1);
    const u16* kb = Ks[step & 1];
    const u16* vb = Vs[step & 1];

    f32x4 s[4];
#pragma unroll
    for (int nf = 0; nf < 4; ++nf) s[nf] = f32x4{0.f, 0.f, 0.f, 0.f};
    __builtin_amdgcn_s_setprio(1);
#pragma unroll
    for (int ks = 0; ks < 4; ++ks) {
#pragma unroll
      for (int nf = 0; nf < 4; ++nf) {
        int r = nf * 16 + lc;
        int gc = ks * 4 + lg;
        bf16x8 kf = *(const bf16x8*)&kb[r * 128 + ((gc ^ (r & 15)) * 8)];
        s[nf] = mfma16(kf, qf[ks], s[nf]);  // swapped: S[kv][q=lc]
      }
    }
    __builtin_amdgcn_s_setprio(0);

    if (step >= 2 * qt) {  // diagonal region (last two steps)
      int q = srow;
#pragma unroll
      for (int nf = 0; nf < 4; ++nf) {
#pragma unroll
        for (int i = 0; i < 4; ++i) {
          int kv = kv0 + nf * 16 + lg * 4 + i;
          if (kv > q) s[nf][i] = -1e30f;
        }
      }
    }

#pragma unroll
    for (int nf = 0; nf < 4; ++nf) {
#pragma unroll
      for (int i = 0; i < 4; ++i) s[nf][i] = exp2_hw(s[nf][i]);
      lsum += s[nf];
      bf16x4 pw = {(__bf16)s[nf][0], (__bf16)s[nf][1], (__bf16)s[nf][2], (__bf16)s[nf][3]};
      *(bf16x4*)&P_lds[w][lc * 72 + nf * 16 + lg * 4] = pw;
    }
    asm volatile("s_waitcnt lgkmcnt(0)" ::: "memory");
    __builtin_amdgcn_sched_barrier(0);

    bf16x8 pa[2];
#pragma unroll
    for (int ksv = 0; ksv < 2; ++ksv)
      pa[ksv] = *(const bf16x8*)&P_lds[w][lc * 72 + ksv * 32 + lg * 8];

    __builtin_amdgcn_s_setprio(1);
#pragma unroll
    for (int nfd = 0; nfd < 8; ++nfd) {
#pragma unroll
      for (int ksv = 0; ksv < 2; ++ksv) {
        int r = nfd * 16 + lc;
        int gc = ksv * 4 + lg;
        bf16x8 vf = *(const bf16x8*)&vb[r * 64 + ((gc ^ (r & 7)) * 8)];
        o[nfd] = mfma16(pa[ksv], vf, o[nfd]);
      }
    }
    __builtin_amdgcn_s_setprio(0);
  }

  float t = lsum[0] + lsum[1] + lsum[2] + lsum[3];
  t += __shfl_xor(t, 16, 64);
  t += __shfl_xor(t, 32, 64);
  float linv[4];
#pragma unroll
  for (int i = 0; i < 4; ++i) linv[i] = 1.0f / __shfl(t, lg * 4 + i, 64);

#pragma unroll
  for (int nfd = 0; nfd < 8; ++nfd)
#pragma unroll
    for (int i = 0; i < 4; ++i) {
      int row = q0 + w * 16 + lg * 4 + i;
      AO[((size_t)(b * 2048 + row) * 32 + h) * 128 + nfd * 16 + lc] =
          f2bf(o[nfd][i] * linv[i]);
    }
}

extern "C" void kernel_launch(void* const* d_in, const int* in_sizes, int n_in,
                              void* d_out, int out_size, void* d_ws, size_t ws_size,
                              hipStream_t stream) {
  const float* x    = (const float*)d_in[0];
  const float* fcos = (const float*)d_in[1];
  const float* fsin = (const float*)d_in[2];
  const float* wq   = (const float*)d_in[3];
  const float* wk   = (const float*)d_in[4];
  const float* wv   = (const float*)d_in[5];
  const float* wo   = (const float*)d_in[6];
  float* out = (float*)d_out;

  char* ws = (char*)d_ws;
  u16* xb  = (u16*)(ws + 0);             // x bf16  -> later AO
  u16* wqb = (u16*)(ws + 41943040ull);   // wq bf16 -> later wo bf16
  u16* wkb = (u16*)(ws + 83886080ull);   // [wk; wv] CONTIGUOUS (wkv = [2048][5120])
  u16* wvb = (u16*)(ws + 94371840ull);
  u16* Qb  = (u16*)(ws + 104857600ull);
  u16* Kb  = (u16*)(ws + 138412032ull);  // [Kb; VTb] CONTIGUOUS (VT at +4Mi elems)
  u16* VTb = (u16*)(ws + 146800640ull);  // total 155,189,248 B
  u16* AOb = xb;
  u16* wob = wqb;

  // one launch converts x, wq, wk, wv (wo waits: its dst aliases wq's slot)
  cvt4_kernel<<<dim3(2048), dim3(256), 0, stream>>>(
      (const float4*)x, (const float4*)wq, (const float4*)wk, (const float4*)wv,
      (uint2*)xb, (uint2*)wqb, (uint2*)wkb, (uint2*)wvb,
      2 * 2048 * 5120 / 4, 4096 * 5120 / 4, 1024 * 5120 / 4, 1024 * 5120 / 4);

  dim3 blk(256);
  gemm256<0><<<dim3(16, 16), dim3(512), 0, stream>>>(xb, wqb, Qb, 4096, 4096, 5120);
  // merged K+V projection: gemm_bt with B=[wk;wv], N=2048; MODE 3 epilogue
  gemm_bt<3><<<dim3(16, 32), blk, 0, stream>>>(xb, wkb, Kb, 4096, 2048, 5120);

  cvt_kernel<<<dim3(5242880 / 256), blk, 0, stream>>>((const float4*)wo, (uint2*)wob,
                                                      5242880);  // wq dead; reuse slot

  // K-RoPE (proven kernel); Q-RoPE (+ scale) is fused into attn_kernel.
  rope_kernel<<<dim3(2097152 / 256), blk, 0, stream>>>(Kb, fcos, fsin, 3, 1.0f, 2097152);

  attn_kernel<<<dim3(16, 32, 2), dim3(512), 0, stream>>>(Qb, Kb, VTb, fcos, fsin, AOb);

  gemm256<1><<<dim3(20, 16), dim3(512), 0, stream>>>(AOb, wob, out, 4096, 5120, 4096);
}

// Round 29
// 723.148 us; speedup vs baseline: 1.0026x; 1.0003x over previous
//
#include <hip/hip_runtime.h>

// SelfAttention: x[2,2048,5120] -> QKV proj -> RoPE -> causal GQA attention -> out proj
// All matmuls in bf16 MFMA (16x16x32), f32 accum. Tolerance is bf16-grade (0.148 absmax).
// FINAL: proven configuration (724 us, absmax 0.039, reproduced 12x: r14/17/19-28).
// Attn LDS layout is load-bearing: DO NOT modify P_lds/Ks/Vs geometry (occupancy
// experiments raced). cvt5 merge regressed (r18); separate wo convert is faster.

typedef unsigned short u16;
typedef __bf16 bf16x8 __attribute__((ext_vector_type(8)));
typedef __bf16 bf16x4 __attribute__((ext_vector_type(4)));
typedef float f32x4 __attribute__((ext_vector_type(4)));

__device__ __forceinline__ u16 f2bf(float f) {
  unsigned u = __builtin_bit_cast(unsigned, f);
  u += 0x7fff + ((u >> 16) & 1);   // RNE
  return (u16)(u >> 16);
}
__device__ __forceinline__ float bf2f(u16 h) {
  unsigned u = ((unsigned)h) << 16;
  return __builtin_bit_cast(float, u);
}

__device__ __forceinline__ float exp2_hw(float x) {
#if __has_builtin(__builtin_amdgcn_exp2f)
  return __builtin_amdgcn_exp2f(x);   // v_exp_f32: D = 2^S0
#else
  return __expf(x * 0.6931471805599453f);
#endif
}

__device__ __forceinline__ void gload_lds16(const u16* g, u16* lds) {
  __builtin_amdgcn_global_load_lds(
      (const __attribute__((address_space(1))) void*)g,
      (__attribute__((address_space(3))) void*)lds, 16, 0, 0);
}

__device__ __forceinline__ f32x4 mfma16(bf16x8 a, bf16x8 b, f32x4 c) {
  return __builtin_amdgcn_mfma_f32_16x16x32_bf16(a, b, c, 0, 0, 0);
}

#define VMW(N) asm volatile("s_waitcnt vmcnt(" #N ")" ::: "memory")
#define BAR()  __builtin_amdgcn_s_barrier()

// ---------------- f32 -> bf16 bulk convert (single, 4 segments) ----------------
__global__ __launch_bounds__(256) void cvt4_kernel(const float4* __restrict__ s0,
                                                   const float4* __restrict__ s1,
                                                   const float4* __restrict__ s2,
                                                   const float4* __restrict__ s3,
                                                   uint2* __restrict__ d0,
                                                   uint2* __restrict__ d1,
                                                   uint2* __restrict__ d2,
                                                   uint2* __restrict__ d3,
                                                   int n0, int n1, int n2, int n3) {
  int total = n0 + n1 + n2 + n3;
  for (int i = blockIdx.x * blockDim.x + threadIdx.x; i < total;
       i += gridDim.x * blockDim.x) {
    const float4* s; uint2* d; int j = i;
    if (j < n0) { s = s0; d = d0; }
    else if ((j -= n0) < n1) { s = s1; d = d1; }
    else if ((j -= n1) < n2) { s = s2; d = d2; }
    else { j -= n2; s = s3; d = d3; }
    float4 v = s[j];
    d[j] = make_uint2((unsigned)f2bf(v.x) | ((unsigned)f2bf(v.y) << 16),
                      (unsigned)f2bf(v.z) | ((unsigned)f2bf(v.w) << 16));
  }
}

// ---------------- f32 -> bf16 bulk convert (single segment, for wo) ------------
__global__ __launch_bounds__(256) void cvt_kernel(const float4* __restrict__ in,
                                                  uint2* __restrict__ out, int n4) {
  int i = blockIdx.x * blockDim.x + threadIdx.x;
  if (i >= n4) return;
  float4 v = in[i];
  unsigned lo = (unsigned)f2bf(v.x) | ((unsigned)f2bf(v.y) << 16);
  unsigned hi = (unsigned)f2bf(v.z) | ((unsigned)f2bf(v.w) << 16);
  out[i] = make_uint2(lo, hi);
}

// ---------------- RoPE in-place on bf16 [*, nheads, 64 pairs] ----------------
__global__ __launch_bounds__(256) void rope_kernel(u16* __restrict__ t,
                                                   const float* __restrict__ fcos,
                                                   const float* __restrict__ fsin,
                                                   int hsh, float scale, int total) {
  int idx = blockIdx.x * blockDim.x + threadIdx.x;
  if (idx >= total) return;
  int j = idx & 63;
  int s = (idx >> (6 + hsh)) & 2047;
  float c = fcos[s * 64 + j], sn = fsin[s * 64 + j];
  unsigned* p = (unsigned*)(t + (size_t)idx * 2);
  unsigned v = *p;
  float tr = bf2f((u16)(v & 0xffffu)), ti = bf2f((u16)(v >> 16));
  float orr = (tr * c - ti * sn) * scale;
  float oi  = (tr * sn + ti * c) * scale;
  *p = (unsigned)f2bf(orr) | ((unsigned)f2bf(oi) << 16);
}

// ---------------- bf16 NT GEMM 128x128 ----------------
// MODE 0: bf16 C[M][N]; MODE 2: transposed V store; MODE 3: merged K|V projection
// (B = [wk;wv] contiguous, N=2048; gn<1024 -> K stride 1024, else VT at +4Mi elems).
template <int MODE>
__global__ __launch_bounds__(256) void gemm_bt(const u16* __restrict__ A,
                                               const u16* __restrict__ B,
                                               void* __restrict__ Cout,
                                               int M, int N, int K) {
  __shared__ u16 As[8192];  // [128][64] bf16, chunk c (16B) of row r stored at c^(r&7)
  __shared__ u16 Bs[8192];
  const int tid = threadIdx.x;
  const int lane = tid & 63, wave = tid >> 6;
  const int wm = wave >> 1, wn = wave & 1;
  int gx = gridDim.x, gy = gridDim.y, nwg = gx * gy;
  int orig = blockIdx.y * gx + blockIdx.x;
  int mb, nb;
  if ((gx & 1) == 0 && (gy & 3) == 0 && (nwg & 7) == 0) {
    // XCDs arranged 4 (m) x 2 (n); per-XCD tile (gy/4) x (gx/2) blocks
    int x = orig & 7, idx = orig >> 3;
    int hy = gy >> 2, qx = gx >> 1;
    mb = (x >> 1) * hy + (idx % hy);
    nb = (x & 1) * qx + (idx / hy);
  } else {
    mb = orig / gx; nb = orig % gx;
  }
  const int m0 = mb * 128, n0 = nb * 128;
  const int lc = lane & 15, lg = lane >> 4;

  f32x4 acc[4][4] = {};
  const int sr = tid >> 3, sc = tid & 7;

  for (int kt = 0; kt < K; kt += 64) {
    __syncthreads();
#pragma unroll
    for (int q = 0; q < 4; ++q) {
      int r = q * 32 + sr;
      int cc = sc ^ (r & 7);
      gload_lds16(A + (size_t)(m0 + r) * K + kt + cc * 8, &As[q * 2048 + tid * 8]);
      gload_lds16(B + (size_t)(n0 + r) * K + kt + cc * 8, &Bs[q * 2048 + tid * 8]);
    }
    __syncthreads();
#pragma unroll
    for (int ks = 0; ks < 2; ++ks) {
      bf16x8 af[4], bfr[4];
#pragma unroll
      for (int m = 0; m < 4; ++m) {
        int r = wm * 64 + m * 16 + lc;
        int gc = ks * 4 + lg;
        af[m] = *(const bf16x8*)&As[r * 64 + ((gc ^ (r & 7)) * 8)];
      }
#pragma unroll
      for (int n = 0; n < 4; ++n) {
        int r = wn * 64 + n * 16 + lc;
        int gc = ks * 4 + lg;
        bfr[n] = *(const bf16x8*)&Bs[r * 64 + ((gc ^ (r & 7)) * 8)];
      }
#pragma unroll
      for (int m = 0; m < 4; ++m)
#pragma unroll
        for (int n = 0; n < 4; ++n)
          acc[m][n] = mfma16(af[m], bfr[n], acc[m][n]);
    }
  }

  // epilogue: C/D layout col=lane&15, row=(lane>>4)*4+i  [m89-verified]
#pragma unroll
  for (int m = 0; m < 4; ++m) {
#pragma unroll
    for (int n = 0; n < 4; ++n) {
#pragma unroll
      for (int i = 0; i < 4; ++i) {
        int gm = m0 + wm * 64 + m * 16 + lg * 4 + i;
        int gn = n0 + wn * 64 + n * 16 + lc;
        float v = acc[m][n][i];
        if (MODE == 0) {
          ((u16*)Cout)[(size_t)gm * N + gn] = f2bf(v);
        } else if (MODE == 2) {
          size_t addr = ((size_t)((gm >> 11) * 8 + (gn >> 7)) * 128 + (gn & 127)) * 2048 +
                        (gm & 2047);
          ((u16*)Cout)[addr] = f2bf(v);
        } else {  // MODE 3: merged K|V
          if (gn < 1024) {
            ((u16*)Cout)[(size_t)gm * 1024 + gn] = f2bf(v);
          } else {
            int gnv = gn - 1024;
            size_t addr = 4194304ull +
                          ((size_t)((gm >> 11) * 8 + (gnv >> 7)) * 128 + (gnv & 127)) * 2048 +
                          (gm & 2047);
            ((u16*)Cout)[addr] = f2bf(v);
          }
        }
      }
    }
  }
}

// ---------------- bf16 NT GEMM 256x256, 4-phase READ-AHEAD pipeline ----------
// (round-14 version — 219 us / ~785 TF, MfmaUtil 33.5%)
template <int OUT_F32>
__global__ __launch_bounds__(512, 2) void gemm256(const u16* __restrict__ A,
                                                  const u16* __restrict__ B,
                                                  void* __restrict__ Cout,
                                                  int M, int N, int K) {
  __shared__ u16 lds[2][2][2][8192];  // [buf][A=0/B=1][half][128*64]
  __shared__ u16 dummy[4096];
  const int tid = threadIdx.x, lane = tid & 63, wave = tid >> 6;
  const int wm = wave >> 2;            // A half (M)
  const int wn = wave & 3;             // N quarter
  const int lc = lane & 15, lg = lane >> 4;
  const int bh = wn >> 1;              // B half this wave reads
  const int bs64 = (wn & 1) * 64;      // row slice within B half
  const int str = tid >> 3, ssc = tid & 7;

  int gx = gridDim.x, gy = gridDim.y;
  int orig = blockIdx.y * gx + blockIdx.x;
  int mb, nb;
  if ((gx & 3) == 0 && (gy & 1) == 0) {
    // XCDs arranged 2 (m) x 4 (n); per-XCD tile (gy/2) x (gx/4) blocks
    int x = orig & 7, idx = orig >> 3;
    int hy = gy >> 1, qx = gx >> 2;
    mb = (x >> 2) * hy + (idx % hy);
    nb = (x & 3) * qx + (idx / hy);
  } else {
    mb = orig / gx; nb = orig % gx;
  }
  const int m0 = mb * 256, n0 = nb * 256;

  auto stageA = [&](int buf, int kcol, int r0, bool real) {
    int r = r0 + str, cc = ssc ^ (r & 7);
    const u16* s = A + (size_t)(m0 + r) * K + kcol + cc * 8;
    u16* d0 = real ? &lds[buf][0][0][r0 * 64] : dummy;
    u16* d1 = real ? &lds[buf][0][1][r0 * 64] : dummy;
    gload_lds16(s, d0 + tid * 8);
    gload_lds16(s + (size_t)128 * K, d1 + tid * 8);
  };
  auto stageB = [&](int buf, int kcol, int half, bool real) {
    int r = str, cc = ssc ^ (r & 7);
    int r2 = 64 + str, cc2 = ssc ^ (r2 & 7);
    const u16* s = B + (size_t)(n0 + half * 128) * K + kcol;
    u16* d0 = real ? &lds[buf][1][half][0] : dummy;
    u16* d1 = real ? &lds[buf][1][half][4096] : dummy;
    gload_lds16(s + (size_t)r * K + cc * 8, d0 + tid * 8);
    gload_lds16(s + (size_t)r2 * K + cc2 * 8, d1 + tid * 8);
  };

  f32x4 acc[8][4] = {};
  bf16x8 afk[4][2], bfk[4][2];

  const int nk = K >> 6;
  stageB(0, 0, 0, true);
  stageA(0, 0, 0, true);
  stageB(0, 0, 1, true);
  stageA(0, 0, 64, true);
  stageB(1, 64, 0, true);
  stageA(1, 64, 0, true);
  VMW(6);
  BAR();
  {  // preload af_lo(0), bfv01(0)
    const u16* Ab = &lds[0][0][wm][0];
    const u16* Bb = &lds[0][1][bh][0];
#pragma unroll
    for (int m = 0; m < 4; ++m)
#pragma unroll
      for (int kg = 0; kg < 2; ++kg) {
        int r = m * 16 + lc;
        afk[m][kg] = *(const bf16x8*)&Ab[r * 64 + (((kg * 4 + lg) ^ (r & 7)) * 8)];
      }
#pragma unroll
    for (int n = 0; n < 2; ++n)
#pragma unroll
      for (int kg = 0; kg < 2; ++kg) {
        int r = bs64 + n * 16 + lc;
        bfk[n][kg] = *(const bf16x8*)&Bb[r * 64 + (((kg * 4 + lg) ^ (r & 7)) * 8)];
      }
  }

  for (int t = 0; t < nk; ++t) {
    const int c = t & 1;
    const int t1 = t + 1, t2 = t + 2;
    const int kc1 = (t1 < nk ? t1 : nk - 1) << 6;
    const int kc2 = (t2 < nk ? t2 : nk - 1) << 6;
    const bool h1 = t1 < nk, h2 = t2 < nk;
    const u16* Ab = &lds[c][0][wm][0];
    const u16* Bb = &lds[c][1][bh][0];
    const u16* Abn = &lds[c ^ 1][0][wm][0];
    const u16* Bbn = &lds[c ^ 1][1][bh][0];

    // ---- p1: MFMA m0-3 x n0-1 ; read bfv23(t) ----
    stageB(t1 & 1, kc1, 1, h1);      // B1(t+1)
    BAR();
    __builtin_amdgcn_s_setprio(1);
#pragma unroll
    for (int m = 0; m < 4; ++m)
#pragma unroll
      for (int n = 0; n < 2; ++n)
#pragma unroll
        for (int kg = 0; kg < 2; ++kg)
          acc[m][n] = mfma16(afk[m][kg], bfk[n][kg], acc[m][n]);
    __builtin_amdgcn_s_setprio(0);
#pragma unroll
    for (int n = 2; n < 4; ++n)
#pragma unroll
      for (int kg = 0; kg < 2; ++kg) {
        int r = bs64 + n * 16 + lc;
        bfk[n][kg] = *(const bf16x8*)&Bb[r * 64 + (((kg * 4 + lg) ^ (r & 7)) * 8)];
      }
    BAR();

    // ---- p2: MFMA m0-3 x n2-3 ; read af_hi(t) ----
    VMW(6);                          // drains Ah(t) (4-phase slack)
    stageA(t1 & 1, kc1, 64, h1);     // Ah(t+1)
    BAR();
    __builtin_amdgcn_s_setprio(1);
#pragma unroll
    for (int m = 0; m < 4; ++m)
#pragma unroll
      for (int n = 2; n < 4; ++n)
#pragma unroll
        for (int kg = 0; kg < 2; ++kg)
          acc[m][n] = mfma16(afk[m][kg], bfk[n][kg], acc[m][n]);
    __builtin_amdgcn_s_setprio(0);
#pragma unroll
    for (int m = 0; m < 4; ++m)
#pragma unroll
      for (int kg = 0; kg < 2; ++kg) {
        int r = 64 + m * 16 + lc;
        afk[m][kg] = *(const bf16x8*)&Ab[r * 64 + (((kg * 4 + lg) ^ (r & 7)) * 8)];
      }
    BAR();

    // ---- p3: MFMA m4-7 x n0-1 ; read bfv01(t+1) from next buf ----
    VMW(2);                          // drains B0(t+1), Al(t+1), B1(t+1)
    stageB(t2 & 1, kc2, 0, h2);      // B0(t+2)
    BAR();
    __builtin_amdgcn_s_setprio(1);
#pragma unroll
    for (int m = 0; m < 4; ++m)
#pragma unroll
      for (int n = 0; n < 2; ++n)
#pragma unroll
        for (int kg = 0; kg < 2; ++kg)
          acc[4 + m][n] = mfma16(afk[m][kg], bfk[n][kg], acc[4 + m][n]);
    __builtin_amdgcn_s_setprio(0);
#pragma unroll
    for (int n = 0; n < 2; ++n)
#pragma unroll
      for (int kg = 0; kg < 2; ++kg) {
        int r = bs64 + n * 16 + lc;
        bfk[n][kg] = *(const bf16x8*)&Bbn[r * 64 + (((kg * 4 + lg) ^ (r & 7)) * 8)];
      }
    BAR();

    // ---- p4: MFMA m4-7 x n2-3 ; read af_lo(t+1) from next buf ----
    stageA(t2 & 1, kc2, 0, h2);      // Al(t+2)
    BAR();
    __builtin_amdgcn_s_setprio(1);
#pragma unroll
    for (int m = 0; m < 4; ++m)
#pragma unroll
      for (int n = 2; n < 4; ++n)
#pragma unroll
        for (int kg = 0; kg < 2; ++kg)
          acc[4 + m][n] = mfma16(afk[m][kg], bfk[n][kg], acc[4 + m][n]);
    __builtin_amdgcn_s_setprio(0);
#pragma unroll
    for (int m = 0; m < 4; ++m)
#pragma unroll
      for (int kg = 0; kg < 2; ++kg) {
        int r = m * 16 + lc;
        afk[m][kg] = *(const bf16x8*)&Abn[r * 64 + (((kg * 4 + lg) ^ (r & 7)) * 8)];
      }
    BAR();
  }

  // epilogue: C/D layout col=lane&15, row=(lane>>4)*4+i
#pragma unroll
  for (int m = 0; m < 8; ++m) {
#pragma unroll
    for (int n = 0; n < 4; ++n) {
#pragma unroll
      for (int i = 0; i < 4; ++i) {
        int gm = m0 + wm * 128 + m * 16 + lg * 4 + i;
        int gn = n0 + wn * 64 + n * 16 + lc;
        float v = acc[m][n][i];
        if (OUT_F32) ((float*)Cout)[(size_t)gm * N + gn] = v;
        else         ((u16*)Cout)[(size_t)gm * N + gn] = f2bf(v);
      }
    }
  }
}

// ---------------- causal GQA flash attention (v5: QBLK=128, fused Q-RoPE) -----
// Proven kernel (absmax 0.039, stable across timed replays, 12 reproductions).
// grid (S/128, HQ, B), 512 thr = 8 waves; P_lds stride 72 — DO NOT CHANGE.
__global__ __launch_bounds__(512) void attn_kernel(const u16* __restrict__ Q,
                                                   const u16* __restrict__ Kg,
                                                   const u16* __restrict__ VT,
                                                   const float* __restrict__ fcos,
                                                   const float* __restrict__ fsin,
                                                   u16* __restrict__ AO) {
  __shared__ u16 Ks[2][8192];        // [kv 64][d 128] per buf, chunk c at c^(r&15)
  __shared__ u16 Vs[2][8192];        // [d 128][kv 64] per buf, chunk c at c^(r&7)
  __shared__ u16 P_lds[8][16 * 72];  // per-wave P [q 16][kv 64], stride 72
  const int tid = threadIdx.x, lane = tid & 63, w = tid >> 6;
  const int qt = (int)gridDim.x - 1 - (int)blockIdx.x;  // heavy blocks first
  const int h = blockIdx.y, b = blockIdx.z;
  const int hkv = h >> 2;
  const int q0 = qt * 128;
  const int lc = lane & 15, lg = lane >> 4;

  // Q fragments + in-register RoPE (+ exp2 scale). Pair j = ks*16 + lg*4 + p.
  const float qs = 0.12751743558818574f;  // log2(e)/sqrt(128)
  const int srow = q0 + w * 16 + lc;      // this lane's q row (within batch)
  bf16x8 qf[4];
  {
    const size_t qrow = ((size_t)(b * 2048 + srow) * 32 + h) * 128;
#pragma unroll
    for (int ks = 0; ks < 4; ++ks) {
      bf16x8 raw = *(const bf16x8*)&Q[qrow + ks * 32 + lg * 8];
      float4 c4 = *(const float4*)&fcos[srow * 64 + ks * 16 + lg * 4];
      float4 s4 = *(const float4*)&fsin[srow * 64 + ks * 16 + lg * 4];
#pragma unroll
      for (int p = 0; p < 4; ++p) {
        float cc = (&c4.x)[p], ss = (&s4.x)[p];
        float tr = (float)raw[2 * p], ti = (float)raw[2 * p + 1];
        qf[ks][2 * p]     = (__bf16)((tr * cc - ti * ss) * qs);
        qf[ks][2 * p + 1] = (__bf16)((tr * ss + ti * cc) * qs);
      }
    }
  }

  f32x4 o[8] = {};
  f32x4 lsum = {0.f, 0.f, 0.f, 0.f};

  const int nsteps = 2 * qt + 2;
  const size_t kpanel = ((size_t)b * 2048 * 8 + hkv) * 128;
  const size_t vpanel = ((size_t)(b * 8 + hkv) * 128) * 2048;

  auto stage = [&](int buf, int step) {
    const int kv0 = step * 64;
#pragma unroll
    for (int p = 0; p < 2; ++p) {  // K tile: 64 rows x 256B, 512 thr
      int r = p * 32 + (tid >> 4);
      int cc = (tid & 15) ^ (r & 15);
      gload_lds16(Kg + kpanel + (size_t)(kv0 + r) * 1024 + cc * 8,
                  &Ks[buf][p * 4096 + tid * 8]);
    }
#pragma unroll
    for (int p = 0; p < 2; ++p) {  // VT tile: 128 rows x 128B
      int r = p * 64 + (tid >> 3);
      int cc = (tid & 7) ^ (r & 7);
      gload_lds16(VT + vpanel + (size_t)r * 2048 + kv0 + cc * 8,
                  &Vs[buf][p * 4096 + tid * 8]);
    }
  };

  stage(0, 0);

  for (int step = 0; step < nsteps; ++step) {
    const int kv0 = step * 64;
    __syncthreads();
    if (step + 1 < nsteps) stage((step + 1) & 1, step + 1);
    const u16* kb = Ks[step & 1];
    const u16* vb = Vs[step & 1];

    f32x4 s[4];
#pragma unroll
    for (int nf = 0; nf < 4; ++nf) s[nf] = f32x4{0.f, 0.f, 0.f, 0.f};
    __builtin_amdgcn_s_setprio(1);
#pragma unroll
    for (int ks = 0; ks < 4; ++ks) {
#pragma unroll
      for (int nf = 0; nf < 4; ++nf) {
        int r = nf * 16 + lc;
        int gc = ks * 4 + lg;
        bf16x8 kf = *(const bf16x8*)&kb[r * 128 + ((gc ^ (r & 15)) * 8)];
        s[nf] = mfma16(kf, qf[ks], s[nf]);  // swapped: S[kv][q=lc]
      }
    }
    __builtin_amdgcn_s_setprio(0);

    if (step >= 2 * qt) {  // diagonal region (last two steps)
      int q = srow;
#pragma unroll
      for (int nf = 0; nf < 4; ++nf) {
#pragma unroll
        for (int i = 0; i < 4; ++i) {
          int kv = kv0 + nf * 16 + lg * 4 + i;
          if (kv > q) s[nf][i] = -1e30f;
        }
      }
    }

#pragma unroll
    for (int nf = 0; nf < 4; ++nf) {
#pragma unroll
      for (int i = 0; i < 4; ++i) s[nf][i] = exp2_hw(s[nf][i]);
      lsum += s[nf];
      bf16x4 pw = {(__bf16)s[nf][0], (__bf16)s[nf][1], (__bf16)s[nf][2], (__bf16)s[nf][3]};
      *(bf16x4*)&P_lds[w][lc * 72 + nf * 16 + lg * 4] = pw;
    }
    asm volatile("s_waitcnt lgkmcnt(0)" ::: "memory");
    __builtin_amdgcn_sched_barrier(0);

    bf16x8 pa[2];
#pragma unroll
    for (int ksv = 0; ksv < 2; ++ksv)
      pa[ksv] = *(const bf16x8*)&P_lds[w][lc * 72 + ksv * 32 + lg * 8];

    __builtin_amdgcn_s_setprio(1);
#pragma unroll
    for (int nfd = 0; nfd < 8; ++nfd) {
#pragma unroll
      for (int ksv = 0; ksv < 2; ++ksv) {
        int r = nfd * 16 + lc;
        int gc = ksv * 4 + lg;
        bf16x8 vf = *(const bf16x8*)&vb[r * 64 + ((gc ^ (r & 7)) * 8)];
        o[nfd] = mfma16(pa[ksv], vf, o[nfd]);
      }
    }
    __builtin_amdgcn_s_setprio(0);
  }

  float t = lsum[0] + lsum[1] + lsum[2] + lsum[3];
  t += __shfl_xor(t, 16, 64);
  t += __shfl_xor(t, 32, 64);
  float linv[4];
#pragma unroll
  for (int i = 0; i < 4; ++i) linv[i] = 1.0f / __shfl(t, lg * 4 + i, 64);

#pragma unroll
  for (int nfd = 0; nfd < 8; ++nfd)
#pragma unroll
    for (int i = 0; i < 4; ++i) {
      int row = q0 + w * 16 + lg * 4 + i;
      AO[((size_t)(b * 2048 + row) * 32 + h) * 128 + nfd * 16 + lc] =
          f2bf(o[nfd][i] * linv[i]);
    }
}

extern "C" void kernel_launch(void* const* d_in, const int* in_sizes, int n_in,
                              void* d_out, int out_size, void* d_ws, size_t ws_size,
                              hipStream_t stream) {
  const float* x    = (const float*)d_in[0];
  const float* fcos = (const float*)d_in[1];
  const float* fsin = (const float*)d_in[2];
  const float* wq   = (const float*)d_in[3];
  const float* wk   = (const float*)d_in[4];
  const float* wv   = (const float*)d_in[5];
  const float* wo   = (const float*)d_in[6];
  float* out = (float*)d_out;

  char* ws = (char*)d_ws;
  u16* xb  = (u16*)(ws + 0);             // x bf16  -> later AO
  u16* wqb = (u16*)(ws + 41943040ull);   // wq bf16 -> later wo bf16
  u16* wkb = (u16*)(ws + 83886080ull);   // [wk; wv] CONTIGUOUS (wkv = [2048][5120])
  u16* wvb = (u16*)(ws + 94371840ull);
  u16* Qb  = (u16*)(ws + 104857600ull);
  u16* Kb  = (u16*)(ws + 138412032ull);  // [Kb; VTb] CONTIGUOUS (VT at +4Mi elems)
  u16* VTb = (u16*)(ws + 146800640ull);  // total 155,189,248 B
  u16* AOb = xb;
  u16* wob = wqb;

  // one launch converts x, wq, wk, wv (wo waits: its dst aliases wq's slot)
  cvt4_kernel<<<dim3(2048), dim3(256), 0, stream>>>(
      (const float4*)x, (const float4*)wq, (const float4*)wk, (const float4*)wv,
      (uint2*)xb, (uint2*)wqb, (uint2*)wkb, (uint2*)wvb,
      2 * 2048 * 5120 / 4, 4096 * 5120 / 4, 1024 * 5120 / 4, 1024 * 5120 / 4);

  dim3 blk(256);
  gemm256<0><<<dim3(16, 16), dim3(512), 0, stream>>>(xb, wqb, Qb, 4096, 4096, 5120);
  // merged K+V projection: gemm_bt with B=[wk;wv], N=2048; MODE 3 epilogue
  gemm_bt<3><<<dim3(16, 32), blk, 0, stream>>>(xb, wkb, Kb, 4096, 2048, 5120);

  cvt_kernel<<<dim3(5242880 / 256), blk, 0, stream>>>((const float4*)wo, (uint2*)wob,
                                                      5242880);  // wq dead; reuse slot

  // K-RoPE (proven kernel); Q-RoPE (+ scale) is fused into attn_kernel.
  rope_kernel<<<dim3(2097152 / 256), blk, 0, stream>>>(Kb, fcos, fsin, 3, 1.0f, 2097152);

  attn_kernel<<<dim3(16, 32, 2), dim3(512), 0, stream>>>(Qb, Kb, VTb, fcos, fsin, AOb);

  gemm256<1><<<dim3(20, 16), dim3(512), 0, stream>>>(AOb, wob, out, 4096, 5120, 4096);
}